// Round 6
// baseline (195.612 us; speedup 1.0000x reference)
//
#include <hip/hip_runtime.h>
#include <math.h>

#define NCAM 6
#define BSZ 2
#define SQL 1024
#define SKL 1680
#define NHEAD 4
#define DHEAD 32
// 1/sqrt(32) * log2(e)  (folded into Q so softmax uses exp2 directly)
#define QSCALE 0.25503494f

typedef unsigned short ushort_t;
typedef unsigned int uint_t;
typedef __attribute__((ext_vector_type(8))) short short8;   // 8 bf16
typedef __attribute__((ext_vector_type(4))) float f32x4;    // MFMA C/D frag

#define MFMA16 __builtin_amdgcn_mfma_f32_16x16x32_bf16

__device__ __forceinline__ ushort_t f2bf(float x) {
  uint_t u = __builtin_bit_cast(uint_t, x);
  u += 0x7FFFu + ((u >> 16) & 1u);   // RNE
  return (ushort_t)(u >> 16);
}

// exact-grade GELU: erf via Abramowitz-Stegun 7.1.26 (|err|<=1.5e-7)
__device__ __forceinline__ float fast_gelu(float x) {
  const float ax = fabsf(x) * 0.70710678118654752f;
  const float tt = __builtin_amdgcn_rcpf(fmaf(0.3275911f, ax, 1.f));
  float poly = fmaf(tt, 1.061405429f, -1.453152027f);
  poly = fmaf(tt, poly, 1.421413741f);
  poly = fmaf(tt, poly, -0.284496736f);
  poly = fmaf(tt, poly, 0.254829592f);
  poly *= tt;
  const float e = __builtin_amdgcn_exp2f(-ax * ax * 1.4426950408889634f);
  float er = fmaf(-poly, e, 1.f);
  er = copysignf(er, x);
  return 0.5f * x * (1.f + er);
}

// ---------------------------------------------------------------------------
// prep: fold LN gains into transposed bf16 weights.
// ---------------------------------------------------------------------------
__global__ __launch_bounds__(256) void prep_kernel(
    const float* __restrict__ Wq, const float* __restrict__ qg, const float* __restrict__ qb, const float* __restrict__ bq,
    const float* __restrict__ Wk, const float* __restrict__ kg, const float* __restrict__ kbb, const float* __restrict__ bk,
    const float* __restrict__ Wv, const float* __restrict__ vg, const float* __restrict__ vbb, const float* __restrict__ bv,
    const float* __restrict__ Wp,
    const float* __restrict__ W1, const float* __restrict__ pre_g, const float* __restrict__ pre_b, const float* __restrict__ b1,
    const float* __restrict__ W2,
    ushort_t* WqT, ushort_t* WkT, ushort_t* WvT, ushort_t* WpT, ushort_t* W1T, ushort_t* W2T,
    float* uq, float* bbq, float* uk, float* bbk, float* uv, float* bbv, float* b1p) {
  const int mb = blockIdx.x;
  const float *W, *g = nullptr, *bln = nullptr, *bias = nullptr;
  ushort_t* WT; float *u = nullptr, *bb = nullptr;
  int kin = 128, nout = 128, ob;
  if (mb < 4)       { W=Wq; g=qg; bln=qb;   bias=bq; WT=WqT; u=uq; bb=bbq; ob=mb*32; }
  else if (mb < 8)  { W=Wk; g=kg; bln=kbb;  bias=bk; WT=WkT; u=uk; bb=bbk; ob=(mb-4)*32; }
  else if (mb < 12) { W=Wv; g=vg; bln=vbb;  bias=bv; WT=WvT; u=uv; bb=bbv; ob=(mb-8)*32; }
  else if (mb < 16) { W=Wp; WT=WpT; ob=(mb-12)*32; }
  else if (mb < 24) { W=W1; g=pre_g; bln=pre_b; bias=b1; WT=W1T; bb=b1p; nout=256; ob=(mb-16)*32; }
  else              { W=W2; WT=W2T; kin=256; ob=(mb-24)*32; }
  const int t = threadIdx.x;
  const int oc = t & 31, ig = t >> 5;
  const int out = ob + oc;
  const int nper = kin >> 3;
  float su = 0.f, sb = 0.f;
  for (int j = 0; j < nper; ++j) {
    const int in = ig * nper + j;
    const float wv_ = W[(size_t)in * nout + out];
    const float wg = g ? g[in] * wv_ : wv_;
    WT[(size_t)out * kin + in] = f2bf(wg);
    su += wg;
    if (bln) sb += bln[in] * wv_;
  }
  __shared__ float sU[8][32], sB[8][32];
  sU[ig][oc] = su; sB[ig][oc] = sb;
  __syncthreads();
  if (t < 32) {
    float tu = 0.f, tb = 0.f;
#pragma unroll
    for (int i = 0; i < 8; ++i) { tu += sU[i][t]; tb += sB[i][t]; }
    if (u)  u[ob + t] = tu;
    if (bb) bb[ob + t] = tb + (bias ? bias[ob + t] : 0.f);
  }
}

// ---------------------------------------------------------------------------
// proj: bf16 MFMA GEMM on RAW x (LN folded into epilogue).
// ---------------------------------------------------------------------------
__global__ __launch_bounds__(256) void proj_mfma(
    const float* __restrict__ xq, const float* __restrict__ xk, const float* __restrict__ xv,
    const ushort_t* __restrict__ WqT, const ushort_t* __restrict__ WkT, const ushort_t* __restrict__ WvT,
    const float* __restrict__ uq, const float* __restrict__ uk, const float* __restrict__ uv,
    const float* __restrict__ bbq, const float* __restrict__ bbk, const float* __restrict__ bbv,
    ushort_t* __restrict__ Qh, ushort_t* __restrict__ Kh, ushort_t* __restrict__ Vt) {
  int blk = blockIdx.x;
  const float* x; const ushort_t* WT; const float* u; const float* bb;
  ushort_t* out; int S, ntile, vmode; float oscale;
  if (blk < 192)      { x=xq; WT=WqT; u=uq; bb=bbq; out=Qh; S=SQL; ntile=16; vmode=0; oscale=QSCALE; }
  else if (blk < 516) { blk-=192; x=xk; WT=WkT; u=uk; bb=bbk; out=Kh; S=SKL; ntile=27; vmode=0; oscale=1.f; }
  else                { blk-=516; x=xv; WT=WvT; u=uv; bb=bbv; out=Vt; S=SKL; ntile=27; vmode=1; oscale=1.f; }
  const int bn = blk / ntile;
  const int pos0 = (blk - bn * ntile) * 64;
  int valid = S - pos0; if (valid > 64) valid = 64;   // 64 or 16

  const int t = threadIdx.x;
  __shared__ ushort_t sX[64 * 128];
  __shared__ float sS1[16][64], sS2[16][64];
  __shared__ float sMu[64], sRs[64];

  {  // stage + stats: thread = (pos-quad 0..15, ch-group 0..15)
    const int posq = t & 15, chg = t >> 4;
    int lp4 = 4 * posq; if (lp4 >= valid) lp4 = valid - 4;  // clamp (dup writes benign)
    const float* xb = x + ((size_t)bn * 128 + chg * 8) * S + pos0 + lp4;
    float v[8][4];
#pragma unroll
    for (int i = 0; i < 8; ++i) {
      const float4 f = *((const float4*)(xb + (size_t)i * S));
      v[i][0] = f.x; v[i][1] = f.y; v[i][2] = f.z; v[i][3] = f.w;
    }
#pragma unroll
    for (int j = 0; j < 4; ++j) {
      float s1 = 0.f, s2 = 0.f;
#pragma unroll
      for (int i = 0; i < 8; ++i) { s1 += v[i][j]; s2 += v[i][j] * v[i][j]; }
      sS1[chg][lp4 + j] = s1; sS2[chg][lp4 + j] = s2;
    }
#pragma unroll
    for (int j = 0; j < 4; ++j) {
      const int pos = lp4 + j;
      short8 pk;
#pragma unroll
      for (int i = 0; i < 8; ++i) pk[i] = (short)f2bf(v[i][j]);
      const int phys = chg ^ (pos & 7);
      *((short8*)&sX[pos * 128 + phys * 8]) = pk;
    }
  }
  __syncthreads();
  if (t < 64) {
    float a1 = 0.f, a2 = 0.f;
#pragma unroll
    for (int g = 0; g < 16; ++g) { a1 += sS1[g][t]; a2 += sS2[g][t]; }
    const float mu = a1 * (1.f / 128.f);
    sMu[t] = mu; sRs[t] = rsqrtf(a2 * (1.f / 128.f) - mu * mu + 1e-5f);
  }
  __syncthreads();

  const int w = t >> 6, l = t & 63, lq = l & 15, quad = l >> 4;
  short8 af[2][4];
#pragma unroll
  for (int ms = 0; ms < 2; ++ms)
#pragma unroll
    for (int kk = 0; kk < 4; ++kk)
      af[ms][kk] = *((const short8*)(WT + (size_t)(w * 32 + ms * 16 + lq) * 128 + quad * 8 + kk * 32));
  f32x4 acc[4][2];
#pragma unroll
  for (int ns = 0; ns < 4; ++ns)
#pragma unroll
    for (int ms = 0; ms < 2; ++ms) acc[ns][ms] = (f32x4){0.f, 0.f, 0.f, 0.f};
#pragma unroll
  for (int ns = 0; ns < 4; ++ns) {
    short8 bf[4];
#pragma unroll
    for (int kk = 0; kk < 4; ++kk) {
      const int phys = (quad + 4 * kk) ^ (lq & 7);
      bf[kk] = *((const short8*)&sX[(ns * 16 + lq) * 128 + phys * 8]);
    }
#pragma unroll
    for (int ms = 0; ms < 2; ++ms) {
      f32x4 a = acc[ns][ms];
#pragma unroll
      for (int kk = 0; kk < 4; ++kk) a = MFMA16(af[ms][kk], bf[kk], a, 0, 0, 0);
      acc[ns][ms] = a;
    }
  }

  const int b_ = bn / NCAM, cam = bn - b_ * NCAM;
  const size_t slab = (size_t)((b_ * NHEAD + w) * NCAM + cam);
#pragma unroll
  for (int ms = 0; ms < 2; ++ms) {
    float uu[4], bv_[4];
#pragma unroll
    for (int r = 0; r < 4; ++r) {
      const int og = w * 32 + ms * 16 + quad * 4 + r;
      uu[r] = u[og]; bv_[r] = bb[og];
    }
#pragma unroll
    for (int ns = 0; ns < 4; ++ns) {
      const int p = ns * 16 + lq;
      if (p < valid) {
        const float mu = sMu[p], rs = sRs[p];
        float val[4];
#pragma unroll
        for (int r = 0; r < 4; ++r)
          val[r] = ((acc[ns][ms][r] - mu * uu[r]) * rs + bv_[r]) * oscale;
        if (vmode == 0) {
          ushort_t e0 = f2bf(val[0]), e1 = f2bf(val[1]), e2 = f2bf(val[2]), e3 = f2bf(val[3]);
          ushort_t* orow = out + (slab * S + pos0 + p) * 32 + ms * 16 + quad * 4;
          *((uint_t*)orow) = (uint_t)e0 | ((uint_t)e1 << 16);
          *((uint_t*)(orow + 2)) = (uint_t)e2 | ((uint_t)e3 << 16);
        } else {
#pragma unroll
          for (int r = 0; r < 4; ++r)
            out[(slab * 32 + ms * 16 + quad * 4 + r) * (size_t)SKL + pos0 + p] = f2bf(val[r]);
        }
      }
    }
  }
}

// ---------------------------------------------------------------------------
// MFMA flash attention, no-max softmax (exp2; scale folded into Q).
// Grid 256 (bm in low 3 bits -> XCD L2 locality), 512 thr = 8 waves.
// Wave w: cam-triple (w>>2), key-quarter (w&3), TWO Q frags (q0, q0+16).
// FULLY UNROLLED tile loop (21 / 18 tiles) so the compiler hoists K/V L2
// loads across tiles; sP double-buffered by tile parity to decouple the
// exp->ds_write of tile t+1 from the pending ds_read of tile t.
// ---------------------------------------------------------------------------
__global__ __launch_bounds__(512, 1) void attn_mfma(
    const ushort_t* __restrict__ Qh, const ushort_t* __restrict__ Kh,
    const ushort_t* __restrict__ Vt, ushort_t* __restrict__ Ab) {
  const int t = threadIdx.x;
  const int w = t >> 6, l = t & 63;
  const int lq = l & 15, quad = l >> 4;
  const int bm = blockIdx.x & 7;
  const int q0 = (blockIdx.x >> 3) * 32;
  const int camg = w >> 2, kq = w & 3;
  const int kstart = kq * 448;

  __shared__ ushort_t sP[8][2][2][16][72];   // [wave][buf][frag][q][key]
  __shared__ float sO[8][2][16][36];
  __shared__ float sL[8][2][16];

  f32x4 oA0 = {0.f,0.f,0.f,0.f}, oA1 = {0.f,0.f,0.f,0.f};
  f32x4 oB0 = {0.f,0.f,0.f,0.f}, oB1 = {0.f,0.f,0.f,0.f};
  float lA = 0.f, lB = 0.f;

  auto tile_full = [&](const ushort_t* Kb, const ushort_t* Vb, int kb, int buf,
                       short8 qfA, short8 qfB) {
    short8 kf[4];
#pragma unroll
    for (int st = 0; st < 4; ++st)
      kf[st] = *((const short8*)(Kb + (size_t)(kb + st * 16 + lq) * 32 + quad * 8));
    const short8 v00 = *((const short8*)(Vb + (size_t)lq * SKL + kb + quad * 8));
    const short8 v01 = *((const short8*)(Vb + (size_t)lq * SKL + kb + 32 + quad * 8));
    const short8 v10 = *((const short8*)(Vb + (size_t)(16 + lq) * SKL + kb + quad * 8));
    const short8 v11 = *((const short8*)(Vb + (size_t)(16 + lq) * SKL + kb + 32 + quad * 8));

    f32x4 sA[4], sB[4];
#pragma unroll
    for (int st = 0; st < 4; ++st) {
      f32x4 z = {0.f, 0.f, 0.f, 0.f};
      sA[st] = MFMA16(kf[st], qfA, z, 0, 0, 0);
      sB[st] = MFMA16(kf[st], qfB, z, 0, 0, 0);
    }
    float lsA = 0.f, lsB = 0.f;
#pragma unroll
    for (int st = 0; st < 4; ++st) {
      const float a0 = __builtin_amdgcn_exp2f(sA[st][0]);
      const float a1 = __builtin_amdgcn_exp2f(sA[st][1]);
      const float a2 = __builtin_amdgcn_exp2f(sA[st][2]);
      const float a3 = __builtin_amdgcn_exp2f(sA[st][3]);
      const float b0 = __builtin_amdgcn_exp2f(sB[st][0]);
      const float b1 = __builtin_amdgcn_exp2f(sB[st][1]);
      const float b2 = __builtin_amdgcn_exp2f(sB[st][2]);
      const float b3 = __builtin_amdgcn_exp2f(sB[st][3]);
      lsA += (a0 + a1) + (a2 + a3);
      lsB += (b0 + b1) + (b2 + b3);
      const uint_t pa0 = __builtin_amdgcn_perm(__builtin_bit_cast(uint_t, a1), __builtin_bit_cast(uint_t, a0), 0x07060302u);
      const uint_t pa1 = __builtin_amdgcn_perm(__builtin_bit_cast(uint_t, a3), __builtin_bit_cast(uint_t, a2), 0x07060302u);
      const uint_t pb0 = __builtin_amdgcn_perm(__builtin_bit_cast(uint_t, b1), __builtin_bit_cast(uint_t, b0), 0x07060302u);
      const uint_t pb1 = __builtin_amdgcn_perm(__builtin_bit_cast(uint_t, b3), __builtin_bit_cast(uint_t, b2), 0x07060302u);
      *((uint2*)&sP[w][buf][0][lq][st * 16 + quad * 4]) = make_uint2(pa0, pa1);
      *((uint2*)&sP[w][buf][1][lq][st * 16 + quad * 4]) = make_uint2(pb0, pb1);
    }
    const short8 pfA0 = *((const short8*)&sP[w][buf][0][lq][quad * 8]);
    const short8 pfA1 = *((const short8*)&sP[w][buf][0][lq][32 + quad * 8]);
    const short8 pfB0 = *((const short8*)&sP[w][buf][1][lq][quad * 8]);
    const short8 pfB1 = *((const short8*)&sP[w][buf][1][lq][32 + quad * 8]);
    oA0 = MFMA16(v00, pfA0, oA0, 0, 0, 0);
    oA1 = MFMA16(v10, pfA0, oA1, 0, 0, 0);
    oB0 = MFMA16(v00, pfB0, oB0, 0, 0, 0);
    oB1 = MFMA16(v10, pfB0, oB1, 0, 0, 0);
    oA0 = MFMA16(v01, pfA1, oA0, 0, 0, 0);
    oA1 = MFMA16(v11, pfA1, oA1, 0, 0, 0);
    oB0 = MFMA16(v01, pfB1, oB0, 0, 0, 0);
    oB1 = MFMA16(v11, pfB1, oB1, 0, 0, 0);
    lsA += __shfl_xor(lsA, 16, 64);
    lsA += __shfl_xor(lsA, 32, 64);
    lsB += __shfl_xor(lsB, 16, 64);
    lsB += __shfl_xor(lsB, 32, 64);
    lA += lsA; lB += lsB;
  };

  auto tile_tail = [&](const ushort_t* Kb, const ushort_t* Vb, int kb, int buf,
                       short8 qfA, short8 qfB) {
    const short8 kf = *((const short8*)(Kb + (size_t)(kb + lq) * 32 + quad * 8));
    const short8 v00 = *((const short8*)(Vb + (size_t)lq * SKL + kb + quad * 8));
    const short8 v10 = *((const short8*)(Vb + (size_t)(16 + lq) * SKL + kb + quad * 8));
    f32x4 z = {0.f, 0.f, 0.f, 0.f};
    const f32x4 s0A = MFMA16(kf, qfA, z, 0, 0, 0);
    const f32x4 s0B = MFMA16(kf, qfB, z, 0, 0, 0);
    const float a0 = __builtin_amdgcn_exp2f(s0A[0]);
    const float a1 = __builtin_amdgcn_exp2f(s0A[1]);
    const float a2 = __builtin_amdgcn_exp2f(s0A[2]);
    const float a3 = __builtin_amdgcn_exp2f(s0A[3]);
    const float b0 = __builtin_amdgcn_exp2f(s0B[0]);
    const float b1 = __builtin_amdgcn_exp2f(s0B[1]);
    const float b2 = __builtin_amdgcn_exp2f(s0B[2]);
    const float b3 = __builtin_amdgcn_exp2f(s0B[3]);
    float lsA = (a0 + a1) + (a2 + a3);
    float lsB = (b0 + b1) + (b2 + b3);
    const uint_t pa0 = __builtin_amdgcn_perm(__builtin_bit_cast(uint_t, a1), __builtin_bit_cast(uint_t, a0), 0x07060302u);
    const uint_t pa1 = __builtin_amdgcn_perm(__builtin_bit_cast(uint_t, a3), __builtin_bit_cast(uint_t, a2), 0x07060302u);
    const uint_t pb0 = __builtin_amdgcn_perm(__builtin_bit_cast(uint_t, b1), __builtin_bit_cast(uint_t, b0), 0x07060302u);
    const uint_t pb1 = __builtin_amdgcn_perm(__builtin_bit_cast(uint_t, b3), __builtin_bit_cast(uint_t, b2), 0x07060302u);
    *((uint2*)&sP[w][buf][0][lq][quad * 4]) = make_uint2(pa0, pa1);
    *((uint2*)&sP[w][buf][0][lq][16 + quad * 4]) = make_uint2(0u, 0u);
    *((uint2*)&sP[w][buf][1][lq][quad * 4]) = make_uint2(pb0, pb1);
    *((uint2*)&sP[w][buf][1][lq][16 + quad * 4]) = make_uint2(0u, 0u);
    const short8 pfA0 = *((const short8*)&sP[w][buf][0][lq][quad * 8]);
    const short8 pfB0 = *((const short8*)&sP[w][buf][1][lq][quad * 8]);
    oA0 = MFMA16(v00, pfA0, oA0, 0, 0, 0);
    oA1 = MFMA16(v10, pfA0, oA1, 0, 0, 0);
    oB0 = MFMA16(v00, pfB0, oB0, 0, 0, 0);
    oB1 = MFMA16(v10, pfB0, oB1, 0, 0, 0);
    lsA += __shfl_xor(lsA, 16, 64);
    lsA += __shfl_xor(lsA, 32, 64);
    lsB += __shfl_xor(lsB, 16, 64);
    lsB += __shfl_xor(lsB, 32, 64);
    lA += lsA; lB += lsB;
  };

  if (kq < 3) {
#pragma unroll
    for (int nc = 0; nc < 3; ++nc) {
      const int n = camg * 3 + nc;
      const ushort_t* Kb = Kh + (size_t)(bm * NCAM + n) * SKL * 32;
      const ushort_t* Vb = Vt + (size_t)(bm * NCAM + n) * 32 * SKL;
      const ushort_t* Qb = Qh + ((size_t)(bm * NCAM + n) * SQL + q0) * 32;
      const short8 qfA = *((const short8*)(Qb + (size_t)lq * 32 + quad * 8));
      const short8 qfB = *((const short8*)(Qb + (size_t)(16 + lq) * 32 + quad * 8));
#pragma unroll
      for (int kt = 0; kt < 7; ++kt)
        tile_full(Kb, Vb, kstart + kt * 64, (nc * 7 + kt) & 1, qfA, qfB);
    }
  } else {
#pragma unroll
    for (int nc = 0; nc < 3; ++nc) {
      const int n = camg * 3 + nc;
      const ushort_t* Kb = Kh + (size_t)(bm * NCAM + n) * SKL * 32;
      const ushort_t* Vb = Vt + (size_t)(bm * NCAM + n) * 32 * SKL;
      const ushort_t* Qb = Qh + ((size_t)(bm * NCAM + n) * SQL + q0) * 32;
      const short8 qfA = *((const short8*)(Qb + (size_t)lq * 32 + quad * 8));
      const short8 qfB = *((const short8*)(Qb + (size_t)(16 + lq) * 32 + quad * 8));
#pragma unroll
      for (int kt = 0; kt < 5; ++kt)
        tile_full(Kb, Vb, kstart + kt * 64, kt & 1, qfA, qfB);
      tile_tail(Kb, Vb, kstart + 320, 1, qfA, qfB);
    }
  }

  // combine 8 key-partitions per fragment (pure sums — no max tracking)
  *((f32x4*)&sO[w][0][lq][quad * 4]) = oA0;
  *((f32x4*)&sO[w][0][lq][16 + quad * 4]) = oA1;
  *((f32x4*)&sO[w][1][lq][quad * 4]) = oB0;
  *((f32x4*)&sO[w][1][lq][16 + quad * 4]) = oB1;
  if (l < 16) { sL[w][0][l] = lA; sL[w][1][l] = lB; }
  __syncthreads();
  if (w < 2) {
    const int frag = w;
    float lf = 0.f;
    f32x4 a0 = {0.f, 0.f, 0.f, 0.f}, a1 = {0.f, 0.f, 0.f, 0.f};
#pragma unroll
    for (int ww = 0; ww < 8; ++ww) {
      lf += sL[ww][frag][lq];
      a0 += *((const f32x4*)&sO[ww][frag][lq][quad * 4]);
      a1 += *((const f32x4*)&sO[ww][frag][lq][16 + quad * 4]);
    }
    const float inv = 1.f / lf;
    const int b = bm >> 2, hm = bm & 3;
    ushort_t* op = Ab + ((size_t)b * SQL + q0 + frag * 16 + lq) * 128 + hm * 32 + quad * 4;
    ushort4 w0 = make_ushort4(f2bf(a0[0] * inv), f2bf(a0[1] * inv), f2bf(a0[2] * inv), f2bf(a0[3] * inv));
    ushort4 w1 = make_ushort4(f2bf(a1[0] * inv), f2bf(a1[1] * inv), f2bf(a1[2] * inv), f2bf(a1[3] * inv));
    *((ushort4*)op) = w0;
    *((ushort4*)(op + 16)) = w1;
  }
}

// ---------------------------------------------------------------------------
// post: a@Wp + skip -> preLN -> gelu(n@W1''+b1'')@W2 + res -> postLN -> out.
// 8-position tiles, grid 256 (rows 8..15 are clamped duplicates; writes
// masked to lq<8) -> full-GPU coverage for this latency-chain kernel.
// ---------------------------------------------------------------------------
__global__ __launch_bounds__(256) void post_mfma(
    const ushort_t* __restrict__ Ab, const float* __restrict__ skip,
    const ushort_t* __restrict__ WpT, const float* __restrict__ bp,
    const float* __restrict__ pre_g, const float* __restrict__ pre_b,
    const ushort_t* __restrict__ W1T, const float* __restrict__ b1p,
    const ushort_t* __restrict__ W2T, const float* __restrict__ b2,
    const float* __restrict__ post_g, const float* __restrict__ post_b,
    float* __restrict__ out) {
  const int t = threadIdx.x;
  const int w = t >> 6, l = t & 63, lq = l & 15, quad = l >> 4;
  const int b = blockIdx.x >> 7;
  const int p0 = (blockIdx.x & 127) * 8;
  const int rp = (p0 + lq < SQL) ? (p0 + lq) : (SQL - 1);   // clamped row

  __shared__ float zf[16 * 132];
  __shared__ float sRes[16 * 132];
  __shared__ ushort_t sZb[16 * 128];
  __shared__ ushort_t sH[16 * 256];
  __shared__ float sMu[16], sRs[16];

  // ---- GEMM1: z = a@Wp ----
  f32x4 z[2] = {{0.f,0.f,0.f,0.f},{0.f,0.f,0.f,0.f}};
#pragma unroll
  for (int kk = 0; kk < 4; ++kk) {
    const short8 bfr = *((const short8*)(Ab + ((size_t)b * SQL + rp) * 128 + quad * 8 + kk * 32));
#pragma unroll
    for (int ms = 0; ms < 2; ++ms) {
      const short8 afr = *((const short8*)(WpT + (size_t)(w * 32 + ms * 16 + lq) * 128 + quad * 8 + kk * 32));
      z[ms] = MFMA16(afr, bfr, z[ms], 0, 0, 0);
    }
  }
#pragma unroll
  for (int ms = 0; ms < 2; ++ms)
#pragma unroll
    for (int r = 0; r < 4; ++r) {
      const int o = w * 32 + ms * 16 + quad * 4 + r;
      const int rr = (p0 + lq < SQL) ? (p0 + lq) : (SQL - 1);
      zf[lq * 132 + o] = z[ms][r] + bp[o] + skip[(size_t)b * 131072 + (size_t)o * 1024 + rr];
    }
  __syncthreads();
  if (w == 0) {
    const int pos = l & 15, qr = l >> 4;
    float s1 = 0.f, s2 = 0.f;
#pragma unroll
    for (int j = 0; j < 32; ++j) { const float vv = zf[pos * 132 + qr * 32 + j]; s1 += vv; s2 += vv * vv; }
    s1 += __shfl_xor(s1, 16, 64); s1 += __shfl_xor(s1, 32, 64);
    s2 += __shfl_xor(s2, 16, 64); s2 += __shfl_xor(s2, 32, 64);
    const float mu = s1 * (1.f / 128.f);
    if (qr == 0) { sMu[pos] = mu; sRs[pos] = rsqrtf(s2 * (1.f / 128.f) - mu * mu + 1e-5f); }
  }
  __syncthreads();
  {
    const int pos = t & 15, grp = t >> 4;
    const float mu = sMu[pos], rs = sRs[pos];
    short8 pk;
#pragma unroll
    for (int i = 0; i < 8; ++i) {
      const int ch = grp * 8 + i;
      const float nv = (zf[pos * 132 + ch] - mu) * rs;
      pk[i] = (short)f2bf(nv);
      sRes[pos * 132 + ch] = nv * pre_g[ch] + pre_b[ch];
    }
    *((short8*)&sZb[pos * 128 + (grp ^ (pos & 7)) * 8]) = pk;
  }
  __syncthreads();
  // ---- GEMM2 + gelu ----
  f32x4 h[4];
#pragma unroll
  for (int ms = 0; ms < 4; ++ms) h[ms] = (f32x4){0.f, 0.f, 0.f, 0.f};
  short8 bz[4];
#pragma unroll
  for (int kk = 0; kk < 4; ++kk)
    bz[kk] = *((const short8*)&sZb[lq * 128 + ((quad + 4 * kk) ^ (lq & 7)) * 8]);
#pragma unroll
  for (int ms = 0; ms < 4; ++ms)
#pragma unroll
    for (int kk = 0; kk < 4; ++kk) {
      const short8 afr = *((const short8*)(W1T + (size_t)(w * 64 + ms * 16 + lq) * 128 + quad * 8 + kk * 32));
      h[ms] = MFMA16(afr, bz[kk], h[ms], 0, 0, 0);
    }
#pragma unroll
  for (int ms = 0; ms < 4; ++ms)
#pragma unroll
    for (int r = 0; r < 4; ++r) {
      const int o = w * 64 + ms * 16 + quad * 4 + r;
      const float hv = fast_gelu(h[ms][r] + b1p[o]);
      const int phys = (o >> 3) ^ (lq & 7);
      sH[lq * 256 + phys * 8 + (o & 7)] = f2bf(hv);
    }
  __syncthreads();
  // ---- GEMM3 + residual ----
  f32x4 z2[2] = {{0.f,0.f,0.f,0.f},{0.f,0.f,0.f,0.f}};
#pragma unroll
  for (int kk = 0; kk < 8; ++kk) {
    const short8 bh = *((const short8*)&sH[lq * 256 + ((quad + 4 * kk) ^ (lq & 7)) * 8]);
#pragma unroll
    for (int ms = 0; ms < 2; ++ms) {
      const short8 afr = *((const short8*)(W2T + (size_t)(w * 32 + ms * 16 + lq) * 256 + quad * 8 + kk * 32));
      z2[ms] = MFMA16(afr, bh, z2[ms], 0, 0, 0);
    }
  }
  __syncthreads();
#pragma unroll
  for (int ms = 0; ms < 2; ++ms)
#pragma unroll
    for (int r = 0; r < 4; ++r) {
      const int o = w * 32 + ms * 16 + quad * 4 + r;
      zf[lq * 132 + o] = z2[ms][r] + b2[o] + sRes[lq * 132 + o];
    }
  __syncthreads();
  if (w == 0) {
    const int pos = l & 15, qr = l >> 4;
    float s1 = 0.f, s2 = 0.f;
#pragma unroll
    for (int j = 0; j < 32; ++j) { const float vv = zf[pos * 132 + qr * 32 + j]; s1 += vv; s2 += vv * vv; }
    s1 += __shfl_xor(s1, 16, 64); s1 += __shfl_xor(s1, 32, 64);
    s2 += __shfl_xor(s2, 16, 64); s2 += __shfl_xor(s2, 32, 64);
    const float mu = s1 * (1.f / 128.f);
    if (qr == 0) { sMu[pos] = mu; sRs[pos] = rsqrtf(s2 * (1.f / 128.f) - mu * mu + 1e-5f); }
  }
  __syncthreads();
  {
    const int pos = t & 15, grp = t >> 4;
    if (pos < 8) {
      const float mu = sMu[pos], rs = sRs[pos];
#pragma unroll
      for (int i = 0; i < 8; ++i) {
        const int ch = grp * 8 + i;
        out[(size_t)b * 131072 + (size_t)ch * 1024 + p0 + pos] =
            (zf[pos * 132 + ch] - mu) * rs * post_g[ch] + post_b[ch];
      }
    }
  }
}

// ---------------------------------------------------------------------------
extern "C" void kernel_launch(void* const* d_in, const int* in_sizes, int n_in,
                              void* d_out, int out_size, void* d_ws, size_t ws_size,
                              hipStream_t stream) {
  const float* q_in   = (const float*)d_in[0];
  const float* k_in   = (const float*)d_in[1];
  const float* v_in   = (const float*)d_in[2];
  const float* skip   = (const float*)d_in[3];
  const float* q_ln_g = (const float*)d_in[4];
  const float* q_ln_b = (const float*)d_in[5];
  const float* Wq     = (const float*)d_in[6];
  const float* bq     = (const float*)d_in[7];
  const float* k_ln_g = (const float*)d_in[8];
  const float* k_ln_b = (const float*)d_in[9];
  const float* Wk     = (const float*)d_in[10];
  const float* bk     = (const float*)d_in[11];
  const float* v_ln_g = (const float*)d_in[12];
  const float* v_ln_b = (const float*)d_in[13];
  const float* Wv     = (const float*)d_in[14];
  const float* bv     = (const float*)d_in[15];
  const float* Wp     = (const float*)d_in[16];
  const float* bp     = (const float*)d_in[17];
  const float* pre_g  = (const float*)d_in[18];
  const float* pre_b  = (const float*)d_in[19];
  const float* W1     = (const float*)d_in[20];
  const float* b1     = (const float*)d_in[21];
  const float* W2     = (const float*)d_in[22];
  const float* b2     = (const float*)d_in[23];
  const float* post_g = (const float*)d_in[24];
  const float* post_b = (const float*)d_in[25];

  char* base = (char*)d_ws;
  ushort_t* WqT = (ushort_t*)base; base += 16384 * 2;
  ushort_t* WkT = (ushort_t*)base; base += 16384 * 2;
  ushort_t* WvT = (ushort_t*)base; base += 16384 * 2;
  ushort_t* WpT = (ushort_t*)base; base += 16384 * 2;
  ushort_t* W1T = (ushort_t*)base; base += 32768 * 2;
  ushort_t* W2T = (ushort_t*)base; base += 32768 * 2;
  float* uq  = (float*)base; base += 128 * 4;
  float* bbq = (float*)base; base += 128 * 4;
  float* uk  = (float*)base; base += 128 * 4;
  float* bbk = (float*)base; base += 128 * 4;
  float* uv  = (float*)base; base += 128 * 4;
  float* bbv = (float*)base; base += 128 * 4;
  float* b1p = (float*)base; base += 256 * 4;
  base = (char*)(((size_t)base + 255) & ~(size_t)255);
  ushort_t* Qh = (ushort_t*)base; base += (size_t)1572864 * 2;
  ushort_t* Kh = (ushort_t*)base; base += (size_t)(2580480 + 4096) * 2;
  ushort_t* Vt = (ushort_t*)base; base += (size_t)(2580480 + 4096) * 2;
  ushort_t* Ab = (ushort_t*)base; base += (size_t)262144 * 2;
  float* out = (float*)d_out;

  prep_kernel<<<28, 256, 0, stream>>>(
      Wq, q_ln_g, q_ln_b, bq, Wk, k_ln_g, k_ln_b, bk, Wv, v_ln_g, v_ln_b, bv,
      Wp, W1, pre_g, pre_b, b1, W2,
      WqT, WkT, WvT, WpT, W1T, W2T, uq, bbq, uk, bbk, uv, bbv, b1p);
  proj_mfma<<<840, 256, 0, stream>>>(
      q_in, k_in, v_in, WqT, WkT, WvT, uq, uk, uv, bbq, bbk, bbv, Qh, Kh, Vt);
  attn_mfma<<<256, 512, 0, stream>>>(Qh, Kh, Vt, Ab);
  post_mfma<<<256, 256, 0, stream>>>(
      Ab, skip, WpT, bp, pre_g, pre_b, W1T, b1p, W2T, b2, post_g, post_b, out);
}

// Round 7
// 172.961 us; speedup vs baseline: 1.1310x; 1.1310x over previous
//
#include <hip/hip_runtime.h>
#include <math.h>

#define NCAM 6
#define BSZ 2
#define SQL 1024
#define SKL 1680
#define NHEAD 4
#define DHEAD 32
// 1/sqrt(32) * log2(e)  (folded into Q so softmax uses exp2 directly)
#define QSCALE 0.25503494f

typedef unsigned short ushort_t;
typedef unsigned int uint_t;
typedef __attribute__((ext_vector_type(8))) short short8;   // 8 bf16
typedef __attribute__((ext_vector_type(4))) float f32x4;    // MFMA C/D frag

#define MFMA16 __builtin_amdgcn_mfma_f32_16x16x32_bf16

__device__ __forceinline__ ushort_t f2bf(float x) {
  uint_t u = __builtin_bit_cast(uint_t, x);
  u += 0x7FFFu + ((u >> 16) & 1u);   // RNE
  return (ushort_t)(u >> 16);
}

// exact-grade GELU: erf via Abramowitz-Stegun 7.1.26 (|err|<=1.5e-7)
__device__ __forceinline__ float fast_gelu(float x) {
  const float ax = fabsf(x) * 0.70710678118654752f;
  const float tt = __builtin_amdgcn_rcpf(fmaf(0.3275911f, ax, 1.f));
  float poly = fmaf(tt, 1.061405429f, -1.453152027f);
  poly = fmaf(tt, poly, 1.421413741f);
  poly = fmaf(tt, poly, -0.284496736f);
  poly = fmaf(tt, poly, 0.254829592f);
  poly *= tt;
  const float e = __builtin_amdgcn_exp2f(-ax * ax * 1.4426950408889634f);
  float er = fmaf(-poly, e, 1.f);
  er = copysignf(er, x);
  return 0.5f * x * (1.f + er);
}

// ---------------------------------------------------------------------------
// prep: fold LN gains into transposed bf16 weights.
// ---------------------------------------------------------------------------
__global__ __launch_bounds__(256) void prep_kernel(
    const float* __restrict__ Wq, const float* __restrict__ qg, const float* __restrict__ qb, const float* __restrict__ bq,
    const float* __restrict__ Wk, const float* __restrict__ kg, const float* __restrict__ kbb, const float* __restrict__ bk,
    const float* __restrict__ Wv, const float* __restrict__ vg, const float* __restrict__ vbb, const float* __restrict__ bv,
    const float* __restrict__ Wp,
    const float* __restrict__ W1, const float* __restrict__ pre_g, const float* __restrict__ pre_b, const float* __restrict__ b1,
    const float* __restrict__ W2,
    ushort_t* WqT, ushort_t* WkT, ushort_t* WvT, ushort_t* WpT, ushort_t* W1T, ushort_t* W2T,
    float* uq, float* bbq, float* uk, float* bbk, float* uv, float* bbv, float* b1p) {
  const int mb = blockIdx.x;
  const float *W, *g = nullptr, *bln = nullptr, *bias = nullptr;
  ushort_t* WT; float *u = nullptr, *bb = nullptr;
  int kin = 128, nout = 128, ob;
  if (mb < 4)       { W=Wq; g=qg; bln=qb;   bias=bq; WT=WqT; u=uq; bb=bbq; ob=mb*32; }
  else if (mb < 8)  { W=Wk; g=kg; bln=kbb;  bias=bk; WT=WkT; u=uk; bb=bbk; ob=(mb-4)*32; }
  else if (mb < 12) { W=Wv; g=vg; bln=vbb;  bias=bv; WT=WvT; u=uv; bb=bbv; ob=(mb-8)*32; }
  else if (mb < 16) { W=Wp; WT=WpT; ob=(mb-12)*32; }
  else if (mb < 24) { W=W1; g=pre_g; bln=pre_b; bias=b1; WT=W1T; bb=b1p; nout=256; ob=(mb-16)*32; }
  else              { W=W2; WT=W2T; kin=256; ob=(mb-24)*32; }
  const int t = threadIdx.x;
  const int oc = t & 31, ig = t >> 5;
  const int out = ob + oc;
  const int nper = kin >> 3;
  float su = 0.f, sb = 0.f;
  for (int j = 0; j < nper; ++j) {
    const int in = ig * nper + j;
    const float wv_ = W[(size_t)in * nout + out];
    const float wg = g ? g[in] * wv_ : wv_;
    WT[(size_t)out * kin + in] = f2bf(wg);
    su += wg;
    if (bln) sb += bln[in] * wv_;
  }
  __shared__ float sU[8][32], sB[8][32];
  sU[ig][oc] = su; sB[ig][oc] = sb;
  __syncthreads();
  if (t < 32) {
    float tu = 0.f, tb = 0.f;
#pragma unroll
    for (int i = 0; i < 8; ++i) { tu += sU[i][t]; tb += sB[i][t]; }
    if (u)  u[ob + t] = tu;
    if (bb) bb[ob + t] = tb + (bias ? bias[ob + t] : 0.f);
  }
}

// ---------------------------------------------------------------------------
// proj: bf16 MFMA GEMM on RAW x (LN folded into epilogue).
// ---------------------------------------------------------------------------
__global__ __launch_bounds__(256) void proj_mfma(
    const float* __restrict__ xq, const float* __restrict__ xk, const float* __restrict__ xv,
    const ushort_t* __restrict__ WqT, const ushort_t* __restrict__ WkT, const ushort_t* __restrict__ WvT,
    const float* __restrict__ uq, const float* __restrict__ uk, const float* __restrict__ uv,
    const float* __restrict__ bbq, const float* __restrict__ bbk, const float* __restrict__ bbv,
    ushort_t* __restrict__ Qh, ushort_t* __restrict__ Kh, ushort_t* __restrict__ Vt) {
  int blk = blockIdx.x;
  const float* x; const ushort_t* WT; const float* u; const float* bb;
  ushort_t* out; int S, ntile, vmode; float oscale;
  if (blk < 192)      { x=xq; WT=WqT; u=uq; bb=bbq; out=Qh; S=SQL; ntile=16; vmode=0; oscale=QSCALE; }
  else if (blk < 516) { blk-=192; x=xk; WT=WkT; u=uk; bb=bbk; out=Kh; S=SKL; ntile=27; vmode=0; oscale=1.f; }
  else                { blk-=516; x=xv; WT=WvT; u=uv; bb=bbv; out=Vt; S=SKL; ntile=27; vmode=1; oscale=1.f; }
  const int bn = blk / ntile;
  const int pos0 = (blk - bn * ntile) * 64;
  int valid = S - pos0; if (valid > 64) valid = 64;   // 64 or 16

  const int t = threadIdx.x;
  __shared__ ushort_t sX[64 * 128];
  __shared__ float sS1[16][64], sS2[16][64];
  __shared__ float sMu[64], sRs[64];

  {  // stage + stats: thread = (pos-quad 0..15, ch-group 0..15)
    const int posq = t & 15, chg = t >> 4;
    int lp4 = 4 * posq; if (lp4 >= valid) lp4 = valid - 4;  // clamp (dup writes benign)
    const float* xb = x + ((size_t)bn * 128 + chg * 8) * S + pos0 + lp4;
    float v[8][4];
#pragma unroll
    for (int i = 0; i < 8; ++i) {
      const float4 f = *((const float4*)(xb + (size_t)i * S));
      v[i][0] = f.x; v[i][1] = f.y; v[i][2] = f.z; v[i][3] = f.w;
    }
#pragma unroll
    for (int j = 0; j < 4; ++j) {
      float s1 = 0.f, s2 = 0.f;
#pragma unroll
      for (int i = 0; i < 8; ++i) { s1 += v[i][j]; s2 += v[i][j] * v[i][j]; }
      sS1[chg][lp4 + j] = s1; sS2[chg][lp4 + j] = s2;
    }
#pragma unroll
    for (int j = 0; j < 4; ++j) {
      const int pos = lp4 + j;
      short8 pk;
#pragma unroll
      for (int i = 0; i < 8; ++i) pk[i] = (short)f2bf(v[i][j]);
      const int phys = chg ^ (pos & 7);
      *((short8*)&sX[pos * 128 + phys * 8]) = pk;
    }
  }
  __syncthreads();
  if (t < 64) {
    float a1 = 0.f, a2 = 0.f;
#pragma unroll
    for (int g = 0; g < 16; ++g) { a1 += sS1[g][t]; a2 += sS2[g][t]; }
    const float mu = a1 * (1.f / 128.f);
    sMu[t] = mu; sRs[t] = rsqrtf(a2 * (1.f / 128.f) - mu * mu + 1e-5f);
  }
  __syncthreads();

  const int w = t >> 6, l = t & 63, lq = l & 15, quad = l >> 4;
  short8 af[2][4];
#pragma unroll
  for (int ms = 0; ms < 2; ++ms)
#pragma unroll
    for (int kk = 0; kk < 4; ++kk)
      af[ms][kk] = *((const short8*)(WT + (size_t)(w * 32 + ms * 16 + lq) * 128 + quad * 8 + kk * 32));
  f32x4 acc[4][2];
#pragma unroll
  for (int ns = 0; ns < 4; ++ns)
#pragma unroll
    for (int ms = 0; ms < 2; ++ms) acc[ns][ms] = (f32x4){0.f, 0.f, 0.f, 0.f};
#pragma unroll
  for (int ns = 0; ns < 4; ++ns) {
    short8 bf[4];
#pragma unroll
    for (int kk = 0; kk < 4; ++kk) {
      const int phys = (quad + 4 * kk) ^ (lq & 7);
      bf[kk] = *((const short8*)&sX[(ns * 16 + lq) * 128 + phys * 8]);
    }
#pragma unroll
    for (int ms = 0; ms < 2; ++ms) {
      f32x4 a = acc[ns][ms];
#pragma unroll
      for (int kk = 0; kk < 4; ++kk) a = MFMA16(af[ms][kk], bf[kk], a, 0, 0, 0);
      acc[ns][ms] = a;
    }
  }

  const int b_ = bn / NCAM, cam = bn - b_ * NCAM;
  const size_t slab = (size_t)((b_ * NHEAD + w) * NCAM + cam);
#pragma unroll
  for (int ms = 0; ms < 2; ++ms) {
    float uu[4], bv_[4];
#pragma unroll
    for (int r = 0; r < 4; ++r) {
      const int og = w * 32 + ms * 16 + quad * 4 + r;
      uu[r] = u[og]; bv_[r] = bb[og];
    }
#pragma unroll
    for (int ns = 0; ns < 4; ++ns) {
      const int p = ns * 16 + lq;
      if (p < valid) {
        const float mu = sMu[p], rs = sRs[p];
        float val[4];
#pragma unroll
        for (int r = 0; r < 4; ++r)
          val[r] = ((acc[ns][ms][r] - mu * uu[r]) * rs + bv_[r]) * oscale;
        if (vmode == 0) {
          ushort_t e0 = f2bf(val[0]), e1 = f2bf(val[1]), e2 = f2bf(val[2]), e3 = f2bf(val[3]);
          ushort_t* orow = out + (slab * S + pos0 + p) * 32 + ms * 16 + quad * 4;
          *((uint_t*)orow) = (uint_t)e0 | ((uint_t)e1 << 16);
          *((uint_t*)(orow + 2)) = (uint_t)e2 | ((uint_t)e3 << 16);
        } else {
#pragma unroll
          for (int r = 0; r < 4; ++r)
            out[(slab * 32 + ms * 16 + quad * 4 + r) * (size_t)SKL + pos0 + p] = f2bf(val[r]);
        }
      }
    }
  }
}

// ---------------------------------------------------------------------------
// MFMA flash attention, no-max softmax (exp2; scale folded into Q).
// Grid 256 (bm in low 3 bits -> XCD L2 locality), 512 thr = 8 waves.
// Wave w: cam-triple (w>>2), key-quarter (w&3), TWO Q frags (q0, q0+16).
// ROLLED tile loop (R5 structure, no spills) + one-tile K-register prefetch:
// K feeds QK immediately (critical-path load), V is consumed after the exp
// chain so its latency is already hidden.
// ---------------------------------------------------------------------------
__global__ __launch_bounds__(512, 2) void attn_mfma(
    const ushort_t* __restrict__ Qh, const ushort_t* __restrict__ Kh,
    const ushort_t* __restrict__ Vt, ushort_t* __restrict__ Ab) {
  const int t = threadIdx.x;
  const int w = t >> 6, l = t & 63;
  const int lq = l & 15, quad = l >> 4;
  const int bm = blockIdx.x & 7;
  const int q0 = (blockIdx.x >> 3) * 32;
  const int camg = w >> 2, kq = w & 3;
  const int kstart = kq * 448;
  const int nfull = (kq == 3) ? 5 : 7;

  __shared__ ushort_t sP[8][2][16][72];
  __shared__ float sO[8][2][16][36];
  __shared__ float sL[8][2][16];

  f32x4 oA0 = {0.f,0.f,0.f,0.f}, oA1 = {0.f,0.f,0.f,0.f};
  f32x4 oB0 = {0.f,0.f,0.f,0.f}, oB1 = {0.f,0.f,0.f,0.f};
  float lA = 0.f, lB = 0.f;

  for (int nc = 0; nc < 3; ++nc) {
    const int n = camg * 3 + nc;
    const ushort_t* Kb = Kh + (size_t)(bm * NCAM + n) * SKL * 32;
    const ushort_t* Vb = Vt + (size_t)(bm * NCAM + n) * 32 * SKL;
    const ushort_t* Qbase = Qh + ((size_t)(bm * NCAM + n) * SQL + q0) * 32;
    const short8 qfA = *((const short8*)(Qbase + (size_t)lq * 32 + quad * 8));
    const short8 qfB = *((const short8*)(Qbase + (size_t)(16 + lq) * 32 + quad * 8));

    // prefetch K tile 0 of this camera
    short8 kc[4];
#pragma unroll
    for (int st = 0; st < 4; ++st)
      kc[st] = *((const short8*)(Kb + (size_t)(kstart + st * 16 + lq) * 32 + quad * 8));

    for (int kt = 0; kt < nfull; ++kt) {
      const int kb = kstart + kt * 64;
      // V loads for the current tile (consumed late -> latency hidden)
      const short8 v00 = *((const short8*)(Vb + (size_t)lq * SKL + kb + quad * 8));
      const short8 v01 = *((const short8*)(Vb + (size_t)lq * SKL + kb + 32 + quad * 8));
      const short8 v10 = *((const short8*)(Vb + (size_t)(16 + lq) * SKL + kb + quad * 8));
      const short8 v11 = *((const short8*)(Vb + (size_t)(16 + lq) * SKL + kb + 32 + quad * 8));
      // prefetch next tile's K (wave-uniform branch)
      short8 kn[4] = {kc[0], kc[1], kc[2], kc[3]};
      if (kt + 1 < nfull) {
        const int kbn = kb + 64;
#pragma unroll
        for (int st = 0; st < 4; ++st)
          kn[st] = *((const short8*)(Kb + (size_t)(kbn + st * 16 + lq) * 32 + quad * 8));
      }

      f32x4 sA[4], sB[4];
#pragma unroll
      for (int st = 0; st < 4; ++st) {
        f32x4 z = {0.f, 0.f, 0.f, 0.f};
        sA[st] = MFMA16(kc[st], qfA, z, 0, 0, 0);
        sB[st] = MFMA16(kc[st], qfB, z, 0, 0, 0);
      }
      float lsA = 0.f, lsB = 0.f;
#pragma unroll
      for (int st = 0; st < 4; ++st) {
        const float a0 = __builtin_amdgcn_exp2f(sA[st][0]);
        const float a1 = __builtin_amdgcn_exp2f(sA[st][1]);
        const float a2 = __builtin_amdgcn_exp2f(sA[st][2]);
        const float a3 = __builtin_amdgcn_exp2f(sA[st][3]);
        const float b0 = __builtin_amdgcn_exp2f(sB[st][0]);
        const float b1 = __builtin_amdgcn_exp2f(sB[st][1]);
        const float b2 = __builtin_amdgcn_exp2f(sB[st][2]);
        const float b3 = __builtin_amdgcn_exp2f(sB[st][3]);
        lsA += (a0 + a1) + (a2 + a3);
        lsB += (b0 + b1) + (b2 + b3);
        const uint_t pa0 = __builtin_amdgcn_perm(__builtin_bit_cast(uint_t, a1), __builtin_bit_cast(uint_t, a0), 0x07060302u);
        const uint_t pa1 = __builtin_amdgcn_perm(__builtin_bit_cast(uint_t, a3), __builtin_bit_cast(uint_t, a2), 0x07060302u);
        const uint_t pb0 = __builtin_amdgcn_perm(__builtin_bit_cast(uint_t, b1), __builtin_bit_cast(uint_t, b0), 0x07060302u);
        const uint_t pb1 = __builtin_amdgcn_perm(__builtin_bit_cast(uint_t, b3), __builtin_bit_cast(uint_t, b2), 0x07060302u);
        *((uint2*)&sP[w][0][lq][st * 16 + quad * 4]) = make_uint2(pa0, pa1);
        *((uint2*)&sP[w][1][lq][st * 16 + quad * 4]) = make_uint2(pb0, pb1);
      }
      const short8 pfA0 = *((const short8*)&sP[w][0][lq][quad * 8]);
      const short8 pfA1 = *((const short8*)&sP[w][0][lq][32 + quad * 8]);
      const short8 pfB0 = *((const short8*)&sP[w][1][lq][quad * 8]);
      const short8 pfB1 = *((const short8*)&sP[w][1][lq][32 + quad * 8]);
      oA0 = MFMA16(v00, pfA0, oA0, 0, 0, 0);
      oA1 = MFMA16(v10, pfA0, oA1, 0, 0, 0);
      oB0 = MFMA16(v00, pfB0, oB0, 0, 0, 0);
      oB1 = MFMA16(v10, pfB0, oB1, 0, 0, 0);
      oA0 = MFMA16(v01, pfA1, oA0, 0, 0, 0);
      oA1 = MFMA16(v11, pfA1, oA1, 0, 0, 0);
      oB0 = MFMA16(v01, pfB1, oB0, 0, 0, 0);
      oB1 = MFMA16(v11, pfB1, oB1, 0, 0, 0);
      lsA += __shfl_xor(lsA, 16, 64);
      lsA += __shfl_xor(lsA, 32, 64);
      lsB += __shfl_xor(lsB, 16, 64);
      lsB += __shfl_xor(lsB, 32, 64);
      lA += lsA; lB += lsB;
#pragma unroll
      for (int st = 0; st < 4; ++st) kc[st] = kn[st];
    }

    if (kq == 3) {  // 16-key tail (keys 1664..1679)
      const int kb = kstart + 320;
      const short8 kf = *((const short8*)(Kb + (size_t)(kb + lq) * 32 + quad * 8));
      const short8 v00 = *((const short8*)(Vb + (size_t)lq * SKL + kb + quad * 8));
      const short8 v10 = *((const short8*)(Vb + (size_t)(16 + lq) * SKL + kb + quad * 8));
      f32x4 z = {0.f, 0.f, 0.f, 0.f};
      const f32x4 s0A = MFMA16(kf, qfA, z, 0, 0, 0);
      const f32x4 s0B = MFMA16(kf, qfB, z, 0, 0, 0);
      const float a0 = __builtin_amdgcn_exp2f(s0A[0]);
      const float a1 = __builtin_amdgcn_exp2f(s0A[1]);
      const float a2 = __builtin_amdgcn_exp2f(s0A[2]);
      const float a3 = __builtin_amdgcn_exp2f(s0A[3]);
      const float b0 = __builtin_amdgcn_exp2f(s0B[0]);
      const float b1 = __builtin_amdgcn_exp2f(s0B[1]);
      const float b2 = __builtin_amdgcn_exp2f(s0B[2]);
      const float b3 = __builtin_amdgcn_exp2f(s0B[3]);
      float lsA = (a0 + a1) + (a2 + a3);
      float lsB = (b0 + b1) + (b2 + b3);
      const uint_t pa0 = __builtin_amdgcn_perm(__builtin_bit_cast(uint_t, a1), __builtin_bit_cast(uint_t, a0), 0x07060302u);
      const uint_t pa1 = __builtin_amdgcn_perm(__builtin_bit_cast(uint_t, a3), __builtin_bit_cast(uint_t, a2), 0x07060302u);
      const uint_t pb0 = __builtin_amdgcn_perm(__builtin_bit_cast(uint_t, b1), __builtin_bit_cast(uint_t, b0), 0x07060302u);
      const uint_t pb1 = __builtin_amdgcn_perm(__builtin_bit_cast(uint_t, b3), __builtin_bit_cast(uint_t, b2), 0x07060302u);
      *((uint2*)&sP[w][0][lq][quad * 4]) = make_uint2(pa0, pa1);
      *((uint2*)&sP[w][0][lq][16 + quad * 4]) = make_uint2(0u, 0u);
      *((uint2*)&sP[w][1][lq][quad * 4]) = make_uint2(pb0, pb1);
      *((uint2*)&sP[w][1][lq][16 + quad * 4]) = make_uint2(0u, 0u);
      const short8 pfA0 = *((const short8*)&sP[w][0][lq][quad * 8]);
      const short8 pfB0 = *((const short8*)&sP[w][1][lq][quad * 8]);
      oA0 = MFMA16(v00, pfA0, oA0, 0, 0, 0);
      oA1 = MFMA16(v10, pfA0, oA1, 0, 0, 0);
      oB0 = MFMA16(v00, pfB0, oB0, 0, 0, 0);
      oB1 = MFMA16(v10, pfB0, oB1, 0, 0, 0);
      lsA += __shfl_xor(lsA, 16, 64);
      lsA += __shfl_xor(lsA, 32, 64);
      lsB += __shfl_xor(lsB, 16, 64);
      lsB += __shfl_xor(lsB, 32, 64);
      lA += lsA; lB += lsB;
    }
  }

  // combine 8 key-partitions per fragment (pure sums — no max tracking)
  *((f32x4*)&sO[w][0][lq][quad * 4]) = oA0;
  *((f32x4*)&sO[w][0][lq][16 + quad * 4]) = oA1;
  *((f32x4*)&sO[w][1][lq][quad * 4]) = oB0;
  *((f32x4*)&sO[w][1][lq][16 + quad * 4]) = oB1;
  if (l < 16) { sL[w][0][l] = lA; sL[w][1][l] = lB; }
  __syncthreads();
  if (w < 2) {
    const int frag = w;
    float lf = 0.f;
    f32x4 a0 = {0.f, 0.f, 0.f, 0.f}, a1 = {0.f, 0.f, 0.f, 0.f};
#pragma unroll
    for (int ww = 0; ww < 8; ++ww) {
      lf += sL[ww][frag][lq];
      a0 += *((const f32x4*)&sO[ww][frag][lq][quad * 4]);
      a1 += *((const f32x4*)&sO[ww][frag][lq][16 + quad * 4]);
    }
    const float inv = 1.f / lf;
    const int b = bm >> 2, hm = bm & 3;
    ushort_t* op = Ab + ((size_t)b * SQL + q0 + frag * 16 + lq) * 128 + hm * 32 + quad * 4;
    ushort4 w0 = make_ushort4(f2bf(a0[0] * inv), f2bf(a0[1] * inv), f2bf(a0[2] * inv), f2bf(a0[3] * inv));
    ushort4 w1 = make_ushort4(f2bf(a1[0] * inv), f2bf(a1[1] * inv), f2bf(a1[2] * inv), f2bf(a1[3] * inv));
    *((ushort4*)op) = w0;
    *((ushort4*)(op + 16)) = w1;
  }
}

// ---------------------------------------------------------------------------
// post: a@Wp + skip -> preLN -> gelu(n@W1''+b1'')@W2 + res -> postLN -> out.
// 8-position tiles, grid 256 (rows 8..15 are clamped duplicates; writes
// masked to lq<8) -> full-GPU coverage for this latency-chain kernel.
// ---------------------------------------------------------------------------
__global__ __launch_bounds__(256) void post_mfma(
    const ushort_t* __restrict__ Ab, const float* __restrict__ skip,
    const ushort_t* __restrict__ WpT, const float* __restrict__ bp,
    const float* __restrict__ pre_g, const float* __restrict__ pre_b,
    const ushort_t* __restrict__ W1T, const float* __restrict__ b1p,
    const ushort_t* __restrict__ W2T, const float* __restrict__ b2,
    const float* __restrict__ post_g, const float* __restrict__ post_b,
    float* __restrict__ out) {
  const int t = threadIdx.x;
  const int w = t >> 6, l = t & 63, lq = l & 15, quad = l >> 4;
  const int b = blockIdx.x >> 7;
  const int p0 = (blockIdx.x & 127) * 8;
  const int rp = (p0 + lq < SQL) ? (p0 + lq) : (SQL - 1);   // clamped row

  __shared__ float zf[16 * 132];
  __shared__ float sRes[16 * 132];
  __shared__ ushort_t sZb[16 * 128];
  __shared__ ushort_t sH[16 * 256];
  __shared__ float sMu[16], sRs[16];

  // ---- GEMM1: z = a@Wp ----
  f32x4 z[2] = {{0.f,0.f,0.f,0.f},{0.f,0.f,0.f,0.f}};
#pragma unroll
  for (int kk = 0; kk < 4; ++kk) {
    const short8 bfr = *((const short8*)(Ab + ((size_t)b * SQL + rp) * 128 + quad * 8 + kk * 32));
#pragma unroll
    for (int ms = 0; ms < 2; ++ms) {
      const short8 afr = *((const short8*)(WpT + (size_t)(w * 32 + ms * 16 + lq) * 128 + quad * 8 + kk * 32));
      z[ms] = MFMA16(afr, bfr, z[ms], 0, 0, 0);
    }
  }
#pragma unroll
  for (int ms = 0; ms < 2; ++ms)
#pragma unroll
    for (int r = 0; r < 4; ++r) {
      const int o = w * 32 + ms * 16 + quad * 4 + r;
      const int rr = (p0 + lq < SQL) ? (p0 + lq) : (SQL - 1);
      zf[lq * 132 + o] = z[ms][r] + bp[o] + skip[(size_t)b * 131072 + (size_t)o * 1024 + rr];
    }
  __syncthreads();
  if (w == 0) {
    const int pos = l & 15, qr = l >> 4;
    float s1 = 0.f, s2 = 0.f;
#pragma unroll
    for (int j = 0; j < 32; ++j) { const float vv = zf[pos * 132 + qr * 32 + j]; s1 += vv; s2 += vv * vv; }
    s1 += __shfl_xor(s1, 16, 64); s1 += __shfl_xor(s1, 32, 64);
    s2 += __shfl_xor(s2, 16, 64); s2 += __shfl_xor(s2, 32, 64);
    const float mu = s1 * (1.f / 128.f);
    if (qr == 0) { sMu[pos] = mu; sRs[pos] = rsqrtf(s2 * (1.f / 128.f) - mu * mu + 1e-5f); }
  }
  __syncthreads();
  {
    const int pos = t & 15, grp = t >> 4;
    const float mu = sMu[pos], rs = sRs[pos];
    short8 pk;
#pragma unroll
    for (int i = 0; i < 8; ++i) {
      const int ch = grp * 8 + i;
      const float nv = (zf[pos * 132 + ch] - mu) * rs;
      pk[i] = (short)f2bf(nv);
      sRes[pos * 132 + ch] = nv * pre_g[ch] + pre_b[ch];
    }
    *((short8*)&sZb[pos * 128 + (grp ^ (pos & 7)) * 8]) = pk;
  }
  __syncthreads();
  // ---- GEMM2 + gelu ----
  f32x4 h[4];
#pragma unroll
  for (int ms = 0; ms < 4; ++ms) h[ms] = (f32x4){0.f, 0.f, 0.f, 0.f};
  short8 bz[4];
#pragma unroll
  for (int kk = 0; kk < 4; ++kk)
    bz[kk] = *((const short8*)&sZb[lq * 128 + ((quad + 4 * kk) ^ (lq & 7)) * 8]);
#pragma unroll
  for (int ms = 0; ms < 4; ++ms)
#pragma unroll
    for (int kk = 0; kk < 4; ++kk) {
      const short8 afr = *((const short8*)(W1T + (size_t)(w * 64 + ms * 16 + lq) * 128 + quad * 8 + kk * 32));
      h[ms] = MFMA16(afr, bz[kk], h[ms], 0, 0, 0);
    }
#pragma unroll
  for (int ms = 0; ms < 4; ++ms)
#pragma unroll
    for (int r = 0; r < 4; ++r) {
      const int o = w * 64 + ms * 16 + quad * 4 + r;
      const float hv = fast_gelu(h[ms][r] + b1p[o]);
      const int phys = (o >> 3) ^ (lq & 7);
      sH[lq * 256 + phys * 8 + (o & 7)] = f2bf(hv);
    }
  __syncthreads();
  // ---- GEMM3 + residual ----
  f32x4 z2[2] = {{0.f,0.f,0.f,0.f},{0.f,0.f,0.f,0.f}};
#pragma unroll
  for (int kk = 0; kk < 8; ++kk) {
    const short8 bh = *((const short8*)&sH[lq * 256 + ((quad + 4 * kk) ^ (lq & 7)) * 8]);
#pragma unroll
    for (int ms = 0; ms < 2; ++ms) {
      const short8 afr = *((const short8*)(W2T + (size_t)(w * 32 + ms * 16 + lq) * 256 + quad * 8 + kk * 32));
      z2[ms] = MFMA16(afr, bh, z2[ms], 0, 0, 0);
    }
  }
  __syncthreads();
#pragma unroll
  for (int ms = 0; ms < 2; ++ms)
#pragma unroll
    for (int r = 0; r < 4; ++r) {
      const int o = w * 32 + ms * 16 + quad * 4 + r;
      zf[lq * 132 + o] = z2[ms][r] + b2[o] + sRes[lq * 132 + o];
    }
  __syncthreads();
  if (w == 0) {
    const int pos = l & 15, qr = l >> 4;
    float s1 = 0.f, s2 = 0.f;
#pragma unroll
    for (int j = 0; j < 32; ++j) { const float vv = zf[pos * 132 + qr * 32 + j]; s1 += vv; s2 += vv * vv; }
    s1 += __shfl_xor(s1, 16, 64); s1 += __shfl_xor(s1, 32, 64);
    s2 += __shfl_xor(s2, 16, 64); s2 += __shfl_xor(s2, 32, 64);
    const float mu = s1 * (1.f / 128.f);
    if (qr == 0) { sMu[pos] = mu; sRs[pos] = rsqrtf(s2 * (1.f / 128.f) - mu * mu + 1e-5f); }
  }
  __syncthreads();
  {
    const int pos = t & 15, grp = t >> 4;
    if (pos < 8) {
      const float mu = sMu[pos], rs = sRs[pos];
#pragma unroll
      for (int i = 0; i < 8; ++i) {
        const int ch = grp * 8 + i;
        out[(size_t)b * 131072 + (size_t)ch * 1024 + p0 + pos] =
            (zf[pos * 132 + ch] - mu) * rs * post_g[ch] + post_b[ch];
      }
    }
  }
}

// ---------------------------------------------------------------------------
extern "C" void kernel_launch(void* const* d_in, const int* in_sizes, int n_in,
                              void* d_out, int out_size, void* d_ws, size_t ws_size,
                              hipStream_t stream) {
  const float* q_in   = (const float*)d_in[0];
  const float* k_in   = (const float*)d_in[1];
  const float* v_in   = (const float*)d_in[2];
  const float* skip   = (const float*)d_in[3];
  const float* q_ln_g = (const float*)d_in[4];
  const float* q_ln_b = (const float*)d_in[5];
  const float* Wq     = (const float*)d_in[6];
  const float* bq     = (const float*)d_in[7];
  const float* k_ln_g = (const float*)d_in[8];
  const float* k_ln_b = (const float*)d_in[9];
  const float* Wk     = (const float*)d_in[10];
  const float* bk     = (const float*)d_in[11];
  const float* v_ln_g = (const float*)d_in[12];
  const float* v_ln_b = (const float*)d_in[13];
  const float* Wv     = (const float*)d_in[14];
  const float* bv     = (const float*)d_in[15];
  const float* Wp     = (const float*)d_in[16];
  const float* bp     = (const float*)d_in[17];
  const float* pre_g  = (const float*)d_in[18];
  const float* pre_b  = (const float*)d_in[19];
  const float* W1     = (const float*)d_in[20];
  const float* b1     = (const float*)d_in[21];
  const float* W2     = (const float*)d_in[22];
  const float* b2     = (const float*)d_in[23];
  const float* post_g = (const float*)d_in[24];
  const float* post_b = (const float*)d_in[25];

  char* base = (char*)d_ws;
  ushort_t* WqT = (ushort_t*)base; base += 16384 * 2;
  ushort_t* WkT = (ushort_t*)base; base += 16384 * 2;
  ushort_t* WvT = (ushort_t*)base; base += 16384 * 2;
  ushort_t* WpT = (ushort_t*)base; base += 16384 * 2;
  ushort_t* W1T = (ushort_t*)base; base += 32768 * 2;
  ushort_t* W2T = (ushort_t*)base; base += 32768 * 2;
  float* uq  = (float*)base; base += 128 * 4;
  float* bbq = (float*)base; base += 128 * 4;
  float* uk  = (float*)base; base += 128 * 4;
  float* bbk = (float*)base; base += 128 * 4;
  float* uv  = (float*)base; base += 128 * 4;
  float* bbv = (float*)base; base += 128 * 4;
  float* b1p = (float*)base; base += 256 * 4;
  base = (char*)(((size_t)base + 255) & ~(size_t)255);
  ushort_t* Qh = (ushort_t*)base; base += (size_t)1572864 * 2;
  ushort_t* Kh = (ushort_t*)base; base += (size_t)(2580480 + 4096) * 2;
  ushort_t* Vt = (ushort_t*)base; base += (size_t)(2580480 + 4096) * 2;
  ushort_t* Ab = (ushort_t*)base; base += (size_t)262144 * 2;
  float* out = (float*)d_out;

  prep_kernel<<<28, 256, 0, stream>>>(
      Wq, q_ln_g, q_ln_b, bq, Wk, k_ln_g, k_ln_b, bk, Wv, v_ln_g, v_ln_b, bv,
      Wp, W1, pre_g, pre_b, b1, W2,
      WqT, WkT, WvT, WpT, W1T, W2T, uq, bbq, uk, bbk, uv, bbv, b1p);
  proj_mfma<<<840, 256, 0, stream>>>(
      q_in, k_in, v_in, WqT, WkT, WvT, uq, uk, uv, bbq, bbk, bbv, Qh, Kh, Vt);
  attn_mfma<<<256, 512, 0, stream>>>(Qh, Kh, Vt, Ab);
  post_mfma<<<256, 256, 0, stream>>>(
      Ab, skip, WpT, bp, pre_g, pre_b, W1T, b1p, W2T, b2, post_g, post_b, out);
}

// Round 8
// 170.695 us; speedup vs baseline: 1.1460x; 1.0133x over previous
//
#include <hip/hip_runtime.h>
#include <math.h>

#define NCAM 6
#define BSZ 2
#define SQL 1024
#define SKL 1680
#define NHEAD 4
#define DHEAD 32
// 1/sqrt(32) * log2(e)  (folded into Q so softmax uses exp2 directly)
#define QSCALE 0.25503494f

typedef unsigned short ushort_t;
typedef unsigned int uint_t;
typedef __attribute__((ext_vector_type(8))) short short8;   // 8 bf16
typedef __attribute__((ext_vector_type(4))) float f32x4;    // MFMA C/D frag

#define MFMA16 __builtin_amdgcn_mfma_f32_16x16x32_bf16

__device__ __forceinline__ ushort_t f2bf(float x) {
  uint_t u = __builtin_bit_cast(uint_t, x);
  u += 0x7FFFu + ((u >> 16) & 1u);   // RNE
  return (ushort_t)(u >> 16);
}

// exact-grade GELU: erf via Abramowitz-Stegun 7.1.26 (|err|<=1.5e-7)
__device__ __forceinline__ float fast_gelu(float x) {
  const float ax = fabsf(x) * 0.70710678118654752f;
  const float tt = __builtin_amdgcn_rcpf(fmaf(0.3275911f, ax, 1.f));
  float poly = fmaf(tt, 1.061405429f, -1.453152027f);
  poly = fmaf(tt, poly, 1.421413741f);
  poly = fmaf(tt, poly, -0.284496736f);
  poly = fmaf(tt, poly, 0.254829592f);
  poly *= tt;
  const float e = __builtin_amdgcn_exp2f(-ax * ax * 1.4426950408889634f);
  float er = fmaf(-poly, e, 1.f);
  er = copysignf(er, x);
  return 0.5f * x * (1.f + er);
}

// ---------------------------------------------------------------------------
// prep: fold LN gains into transposed bf16 weights.
// ---------------------------------------------------------------------------
__global__ __launch_bounds__(256) void prep_kernel(
    const float* __restrict__ Wq, const float* __restrict__ qg, const float* __restrict__ qb, const float* __restrict__ bq,
    const float* __restrict__ Wk, const float* __restrict__ kg, const float* __restrict__ kbb, const float* __restrict__ bk,
    const float* __restrict__ Wv, const float* __restrict__ vg, const float* __restrict__ vbb, const float* __restrict__ bv,
    const float* __restrict__ Wp,
    const float* __restrict__ W1, const float* __restrict__ pre_g, const float* __restrict__ pre_b, const float* __restrict__ b1,
    const float* __restrict__ W2,
    ushort_t* WqT, ushort_t* WkT, ushort_t* WvT, ushort_t* WpT, ushort_t* W1T, ushort_t* W2T,
    float* uq, float* bbq, float* uk, float* bbk, float* uv, float* bbv, float* b1p) {
  const int mb = blockIdx.x;
  const float *W, *g = nullptr, *bln = nullptr, *bias = nullptr;
  ushort_t* WT; float *u = nullptr, *bb = nullptr;
  int kin = 128, nout = 128, ob;
  if (mb < 4)       { W=Wq; g=qg; bln=qb;   bias=bq; WT=WqT; u=uq; bb=bbq; ob=mb*32; }
  else if (mb < 8)  { W=Wk; g=kg; bln=kbb;  bias=bk; WT=WkT; u=uk; bb=bbk; ob=(mb-4)*32; }
  else if (mb < 12) { W=Wv; g=vg; bln=vbb;  bias=bv; WT=WvT; u=uv; bb=bbv; ob=(mb-8)*32; }
  else if (mb < 16) { W=Wp; WT=WpT; ob=(mb-12)*32; }
  else if (mb < 24) { W=W1; g=pre_g; bln=pre_b; bias=b1; WT=W1T; bb=b1p; nout=256; ob=(mb-16)*32; }
  else              { W=W2; WT=W2T; kin=256; ob=(mb-24)*32; }
  const int t = threadIdx.x;
  const int oc = t & 31, ig = t >> 5;
  const int out = ob + oc;
  const int nper = kin >> 3;
  float su = 0.f, sb = 0.f;
  for (int j = 0; j < nper; ++j) {
    const int in = ig * nper + j;
    const float wv_ = W[(size_t)in * nout + out];
    const float wg = g ? g[in] * wv_ : wv_;
    WT[(size_t)out * kin + in] = f2bf(wg);
    su += wg;
    if (bln) sb += bln[in] * wv_;
  }
  __shared__ float sU[8][32], sB[8][32];
  sU[ig][oc] = su; sB[ig][oc] = sb;
  __syncthreads();
  if (t < 32) {
    float tu = 0.f, tb = 0.f;
#pragma unroll
    for (int i = 0; i < 8; ++i) { tu += sU[i][t]; tb += sB[i][t]; }
    if (u)  u[ob + t] = tu;
    if (bb) bb[ob + t] = tb + (bias ? bias[ob + t] : 0.f);
  }
}

// ---------------------------------------------------------------------------
// proj: bf16 MFMA GEMM on RAW x (LN folded into epilogue).
// ---------------------------------------------------------------------------
__global__ __launch_bounds__(256) void proj_mfma(
    const float* __restrict__ xq, const float* __restrict__ xk, const float* __restrict__ xv,
    const ushort_t* __restrict__ WqT, const ushort_t* __restrict__ WkT, const ushort_t* __restrict__ WvT,
    const float* __restrict__ uq, const float* __restrict__ uk, const float* __restrict__ uv,
    const float* __restrict__ bbq, const float* __restrict__ bbk, const float* __restrict__ bbv,
    ushort_t* __restrict__ Qh, ushort_t* __restrict__ Kh, ushort_t* __restrict__ Vt) {
  int blk = blockIdx.x;
  const float* x; const ushort_t* WT; const float* u; const float* bb;
  ushort_t* out; int S, ntile, vmode; float oscale;
  if (blk < 192)      { x=xq; WT=WqT; u=uq; bb=bbq; out=Qh; S=SQL; ntile=16; vmode=0; oscale=QSCALE; }
  else if (blk < 516) { blk-=192; x=xk; WT=WkT; u=uk; bb=bbk; out=Kh; S=SKL; ntile=27; vmode=0; oscale=1.f; }
  else                { blk-=516; x=xv; WT=WvT; u=uv; bb=bbv; out=Vt; S=SKL; ntile=27; vmode=1; oscale=1.f; }
  const int bn = blk / ntile;
  const int pos0 = (blk - bn * ntile) * 64;
  int valid = S - pos0; if (valid > 64) valid = 64;   // 64 or 16

  const int t = threadIdx.x;
  __shared__ ushort_t sX[64 * 128];
  __shared__ float sS1[16][64], sS2[16][64];
  __shared__ float sMu[64], sRs[64];

  {  // stage + stats: thread = (pos-quad 0..15, ch-group 0..15)
    const int posq = t & 15, chg = t >> 4;
    int lp4 = 4 * posq; if (lp4 >= valid) lp4 = valid - 4;  // clamp (dup writes benign)
    const float* xb = x + ((size_t)bn * 128 + chg * 8) * S + pos0 + lp4;
    float v[8][4];
#pragma unroll
    for (int i = 0; i < 8; ++i) {
      const float4 f = *((const float4*)(xb + (size_t)i * S));
      v[i][0] = f.x; v[i][1] = f.y; v[i][2] = f.z; v[i][3] = f.w;
    }
#pragma unroll
    for (int j = 0; j < 4; ++j) {
      float s1 = 0.f, s2 = 0.f;
#pragma unroll
      for (int i = 0; i < 8; ++i) { s1 += v[i][j]; s2 += v[i][j] * v[i][j]; }
      sS1[chg][lp4 + j] = s1; sS2[chg][lp4 + j] = s2;
    }
#pragma unroll
    for (int j = 0; j < 4; ++j) {
      const int pos = lp4 + j;
      short8 pk;
#pragma unroll
      for (int i = 0; i < 8; ++i) pk[i] = (short)f2bf(v[i][j]);
      const int phys = chg ^ (pos & 7);
      *((short8*)&sX[pos * 128 + phys * 8]) = pk;
    }
  }
  __syncthreads();
  if (t < 64) {
    float a1 = 0.f, a2 = 0.f;
#pragma unroll
    for (int g = 0; g < 16; ++g) { a1 += sS1[g][t]; a2 += sS2[g][t]; }
    const float mu = a1 * (1.f / 128.f);
    sMu[t] = mu; sRs[t] = rsqrtf(a2 * (1.f / 128.f) - mu * mu + 1e-5f);
  }
  __syncthreads();

  const int w = t >> 6, l = t & 63, lq = l & 15, quad = l >> 4;
  short8 af[2][4];
#pragma unroll
  for (int ms = 0; ms < 2; ++ms)
#pragma unroll
    for (int kk = 0; kk < 4; ++kk)
      af[ms][kk] = *((const short8*)(WT + (size_t)(w * 32 + ms * 16 + lq) * 128 + quad * 8 + kk * 32));
  f32x4 acc[4][2];
#pragma unroll
  for (int ns = 0; ns < 4; ++ns)
#pragma unroll
    for (int ms = 0; ms < 2; ++ms) acc[ns][ms] = (f32x4){0.f, 0.f, 0.f, 0.f};
#pragma unroll
  for (int ns = 0; ns < 4; ++ns) {
    short8 bf[4];
#pragma unroll
    for (int kk = 0; kk < 4; ++kk) {
      const int phys = (quad + 4 * kk) ^ (lq & 7);
      bf[kk] = *((const short8*)&sX[(ns * 16 + lq) * 128 + phys * 8]);
    }
#pragma unroll
    for (int ms = 0; ms < 2; ++ms) {
      f32x4 a = acc[ns][ms];
#pragma unroll
      for (int kk = 0; kk < 4; ++kk) a = MFMA16(af[ms][kk], bf[kk], a, 0, 0, 0);
      acc[ns][ms] = a;
    }
  }

  const int b_ = bn / NCAM, cam = bn - b_ * NCAM;
  const size_t slab = (size_t)((b_ * NHEAD + w) * NCAM + cam);
#pragma unroll
  for (int ms = 0; ms < 2; ++ms) {
    float uu[4], bv_[4];
#pragma unroll
    for (int r = 0; r < 4; ++r) {
      const int og = w * 32 + ms * 16 + quad * 4 + r;
      uu[r] = u[og]; bv_[r] = bb[og];
    }
#pragma unroll
    for (int ns = 0; ns < 4; ++ns) {
      const int p = ns * 16 + lq;
      if (p < valid) {
        const float mu = sMu[p], rs = sRs[p];
        float val[4];
#pragma unroll
        for (int r = 0; r < 4; ++r)
          val[r] = ((acc[ns][ms][r] - mu * uu[r]) * rs + bv_[r]) * oscale;
        if (vmode == 0) {
          ushort_t e0 = f2bf(val[0]), e1 = f2bf(val[1]), e2 = f2bf(val[2]), e3 = f2bf(val[3]);
          ushort_t* orow = out + (slab * S + pos0 + p) * 32 + ms * 16 + quad * 4;
          *((uint_t*)orow) = (uint_t)e0 | ((uint_t)e1 << 16);
          *((uint_t*)(orow + 2)) = (uint_t)e2 | ((uint_t)e3 << 16);
        } else {
#pragma unroll
          for (int r = 0; r < 4; ++r)
            out[(slab * 32 + ms * 16 + quad * 4 + r) * (size_t)SKL + pos0 + p] = f2bf(val[r]);
        }
      }
    }
  }
}

// ---------------------------------------------------------------------------
// MFMA flash attention, no-max softmax (exp2; scale folded into Q).
// Grid 256 (bm in low 3 bits -> XCD L2 locality), 512 thr = 8 waves.
// Wave w: cam-triple (w>>2), key-quarter (w&3), TWO Q frags (q0, q0+16).
// LDS UNION: sP (main loop) and sO (final combine) alias the same buffer —
// 74,752 B total -> 2 blocks/CU = 16 waves/CU (was 111,616 B -> 1 block/CU).
// A __syncthreads() separates the last sP read from the first sO write.
// ---------------------------------------------------------------------------
__global__ __launch_bounds__(512, 2) void attn_mfma(
    const ushort_t* __restrict__ Qh, const ushort_t* __restrict__ Kh,
    const ushort_t* __restrict__ Vt, ushort_t* __restrict__ Ab) {
  const int t = threadIdx.x;
  const int w = t >> 6, l = t & 63;
  const int lq = l & 15, quad = l >> 4;
  const int bm = blockIdx.x & 7;
  const int q0 = (blockIdx.x >> 3) * 32;
  const int camg = w >> 2, kq = w & 3;
  const int kstart = kq * 448;
  const int nfull = (kq == 3) ? 5 : 7;

  __shared__ __align__(16) unsigned char smem[74752];
  // sP: [8][2][16][72] ushort (36,864 B) — live during the main loop only
  // sO: [8][2][16][36] float (73,728 B) — live at the combine only (aliases sP)
  // sL: [8][2][16] float (1,024 B) at offset 73,728 — non-overlapping
  ushort_t (*sP)[2][16][72] = (ushort_t(*)[2][16][72])smem;
  float (*sO)[2][16][36] = (float(*)[2][16][36])smem;
  float (*sL)[2][16] = (float(*)[2][16])(smem + 73728);

  f32x4 oA0 = {0.f,0.f,0.f,0.f}, oA1 = {0.f,0.f,0.f,0.f};
  f32x4 oB0 = {0.f,0.f,0.f,0.f}, oB1 = {0.f,0.f,0.f,0.f};
  float lA = 0.f, lB = 0.f;

  for (int nc = 0; nc < 3; ++nc) {
    const int n = camg * 3 + nc;
    const ushort_t* Kb = Kh + (size_t)(bm * NCAM + n) * SKL * 32;
    const ushort_t* Vb = Vt + (size_t)(bm * NCAM + n) * 32 * SKL;
    const ushort_t* Qbase = Qh + ((size_t)(bm * NCAM + n) * SQL + q0) * 32;
    const short8 qfA = *((const short8*)(Qbase + (size_t)lq * 32 + quad * 8));
    const short8 qfB = *((const short8*)(Qbase + (size_t)(16 + lq) * 32 + quad * 8));

    // prefetch K tile 0 of this camera
    short8 kc[4];
#pragma unroll
    for (int st = 0; st < 4; ++st)
      kc[st] = *((const short8*)(Kb + (size_t)(kstart + st * 16 + lq) * 32 + quad * 8));

    for (int kt = 0; kt < nfull; ++kt) {
      const int kb = kstart + kt * 64;
      // V loads for the current tile (consumed late -> latency hidden)
      const short8 v00 = *((const short8*)(Vb + (size_t)lq * SKL + kb + quad * 8));
      const short8 v01 = *((const short8*)(Vb + (size_t)lq * SKL + kb + 32 + quad * 8));
      const short8 v10 = *((const short8*)(Vb + (size_t)(16 + lq) * SKL + kb + quad * 8));
      const short8 v11 = *((const short8*)(Vb + (size_t)(16 + lq) * SKL + kb + 32 + quad * 8));
      // prefetch next tile's K (wave-uniform branch)
      short8 kn[4] = {kc[0], kc[1], kc[2], kc[3]};
      if (kt + 1 < nfull) {
        const int kbn = kb + 64;
#pragma unroll
        for (int st = 0; st < 4; ++st)
          kn[st] = *((const short8*)(Kb + (size_t)(kbn + st * 16 + lq) * 32 + quad * 8));
      }

      f32x4 sA[4], sB[4];
#pragma unroll
      for (int st = 0; st < 4; ++st) {
        f32x4 z = {0.f, 0.f, 0.f, 0.f};
        sA[st] = MFMA16(kc[st], qfA, z, 0, 0, 0);
        sB[st] = MFMA16(kc[st], qfB, z, 0, 0, 0);
      }
      float lsA = 0.f, lsB = 0.f;
#pragma unroll
      for (int st = 0; st < 4; ++st) {
        const float a0 = __builtin_amdgcn_exp2f(sA[st][0]);
        const float a1 = __builtin_amdgcn_exp2f(sA[st][1]);
        const float a2 = __builtin_amdgcn_exp2f(sA[st][2]);
        const float a3 = __builtin_amdgcn_exp2f(sA[st][3]);
        const float b0 = __builtin_amdgcn_exp2f(sB[st][0]);
        const float b1 = __builtin_amdgcn_exp2f(sB[st][1]);
        const float b2 = __builtin_amdgcn_exp2f(sB[st][2]);
        const float b3 = __builtin_amdgcn_exp2f(sB[st][3]);
        lsA += (a0 + a1) + (a2 + a3);
        lsB += (b0 + b1) + (b2 + b3);
        const uint_t pa0 = __builtin_amdgcn_perm(__builtin_bit_cast(uint_t, a1), __builtin_bit_cast(uint_t, a0), 0x07060302u);
        const uint_t pa1 = __builtin_amdgcn_perm(__builtin_bit_cast(uint_t, a3), __builtin_bit_cast(uint_t, a2), 0x07060302u);
        const uint_t pb0 = __builtin_amdgcn_perm(__builtin_bit_cast(uint_t, b1), __builtin_bit_cast(uint_t, b0), 0x07060302u);
        const uint_t pb1 = __builtin_amdgcn_perm(__builtin_bit_cast(uint_t, b3), __builtin_bit_cast(uint_t, b2), 0x07060302u);
        *((uint2*)&sP[w][0][lq][st * 16 + quad * 4]) = make_uint2(pa0, pa1);
        *((uint2*)&sP[w][1][lq][st * 16 + quad * 4]) = make_uint2(pb0, pb1);
      }
      const short8 pfA0 = *((const short8*)&sP[w][0][lq][quad * 8]);
      const short8 pfA1 = *((const short8*)&sP[w][0][lq][32 + quad * 8]);
      const short8 pfB0 = *((const short8*)&sP[w][1][lq][quad * 8]);
      const short8 pfB1 = *((const short8*)&sP[w][1][lq][32 + quad * 8]);
      oA0 = MFMA16(v00, pfA0, oA0, 0, 0, 0);
      oA1 = MFMA16(v10, pfA0, oA1, 0, 0, 0);
      oB0 = MFMA16(v00, pfB0, oB0, 0, 0, 0);
      oB1 = MFMA16(v10, pfB0, oB1, 0, 0, 0);
      oA0 = MFMA16(v01, pfA1, oA0, 0, 0, 0);
      oA1 = MFMA16(v11, pfA1, oA1, 0, 0, 0);
      oB0 = MFMA16(v01, pfB1, oB0, 0, 0, 0);
      oB1 = MFMA16(v11, pfB1, oB1, 0, 0, 0);
      lsA += __shfl_xor(lsA, 16, 64);
      lsA += __shfl_xor(lsA, 32, 64);
      lsB += __shfl_xor(lsB, 16, 64);
      lsB += __shfl_xor(lsB, 32, 64);
      lA += lsA; lB += lsB;
#pragma unroll
      for (int st = 0; st < 4; ++st) kc[st] = kn[st];
    }

    if (kq == 3) {  // 16-key tail (keys 1664..1679)
      const int kb = kstart + 320;
      const short8 kf = *((const short8*)(Kb + (size_t)(kb + lq) * 32 + quad * 8));
      const short8 v00 = *((const short8*)(Vb + (size_t)lq * SKL + kb + quad * 8));
      const short8 v10 = *((const short8*)(Vb + (size_t)(16 + lq) * SKL + kb + quad * 8));
      f32x4 z = {0.f, 0.f, 0.f, 0.f};
      const f32x4 s0A = MFMA16(kf, qfA, z, 0, 0, 0);
      const f32x4 s0B = MFMA16(kf, qfB, z, 0, 0, 0);
      const float a0 = __builtin_amdgcn_exp2f(s0A[0]);
      const float a1 = __builtin_amdgcn_exp2f(s0A[1]);
      const float a2 = __builtin_amdgcn_exp2f(s0A[2]);
      const float a3 = __builtin_amdgcn_exp2f(s0A[3]);
      const float b0 = __builtin_amdgcn_exp2f(s0B[0]);
      const float b1 = __builtin_amdgcn_exp2f(s0B[1]);
      const float b2 = __builtin_amdgcn_exp2f(s0B[2]);
      const float b3 = __builtin_amdgcn_exp2f(s0B[3]);
      float lsA = (a0 + a1) + (a2 + a3);
      float lsB = (b0 + b1) + (b2 + b3);
      const uint_t pa0 = __builtin_amdgcn_perm(__builtin_bit_cast(uint_t, a1), __builtin_bit_cast(uint_t, a0), 0x07060302u);
      const uint_t pa1 = __builtin_amdgcn_perm(__builtin_bit_cast(uint_t, a3), __builtin_bit_cast(uint_t, a2), 0x07060302u);
      const uint_t pb0 = __builtin_amdgcn_perm(__builtin_bit_cast(uint_t, b1), __builtin_bit_cast(uint_t, b0), 0x07060302u);
      const uint_t pb1 = __builtin_amdgcn_perm(__builtin_bit_cast(uint_t, b3), __builtin_bit_cast(uint_t, b2), 0x07060302u);
      *((uint2*)&sP[w][0][lq][quad * 4]) = make_uint2(pa0, pa1);
      *((uint2*)&sP[w][0][lq][16 + quad * 4]) = make_uint2(0u, 0u);
      *((uint2*)&sP[w][1][lq][quad * 4]) = make_uint2(pb0, pb1);
      *((uint2*)&sP[w][1][lq][16 + quad * 4]) = make_uint2(0u, 0u);
      const short8 pfA0 = *((const short8*)&sP[w][0][lq][quad * 8]);
      const short8 pfB0 = *((const short8*)&sP[w][1][lq][quad * 8]);
      oA0 = MFMA16(v00, pfA0, oA0, 0, 0, 0);
      oA1 = MFMA16(v10, pfA0, oA1, 0, 0, 0);
      oB0 = MFMA16(v00, pfB0, oB0, 0, 0, 0);
      oB1 = MFMA16(v10, pfB0, oB1, 0, 0, 0);
      lsA += __shfl_xor(lsA, 16, 64);
      lsA += __shfl_xor(lsA, 32, 64);
      lsB += __shfl_xor(lsB, 16, 64);
      lsB += __shfl_xor(lsB, 32, 64);
      lA += lsA; lB += lsB;
    }
  }

  // all waves done with sP before sO overwrites the same bytes
  __syncthreads();
  *((f32x4*)&sO[w][0][lq][quad * 4]) = oA0;
  *((f32x4*)&sO[w][0][lq][16 + quad * 4]) = oA1;
  *((f32x4*)&sO[w][1][lq][quad * 4]) = oB0;
  *((f32x4*)&sO[w][1][lq][16 + quad * 4]) = oB1;
  if (l < 16) { sL[w][0][l] = lA; sL[w][1][l] = lB; }
  __syncthreads();
  if (w < 2) {
    const int frag = w;
    float lf = 0.f;
    f32x4 a0 = {0.f, 0.f, 0.f, 0.f}, a1 = {0.f, 0.f, 0.f, 0.f};
#pragma unroll
    for (int ww = 0; ww < 8; ++ww) {
      lf += sL[ww][frag][lq];
      a0 += *((const f32x4*)&sO[ww][frag][lq][quad * 4]);
      a1 += *((const f32x4*)&sO[ww][frag][lq][16 + quad * 4]);
    }
    const float inv = 1.f / lf;
    const int b = bm >> 2, hm = bm & 3;
    ushort_t* op = Ab + ((size_t)b * SQL + q0 + frag * 16 + lq) * 128 + hm * 32 + quad * 4;
    ushort4 w0 = make_ushort4(f2bf(a0[0] * inv), f2bf(a0[1] * inv), f2bf(a0[2] * inv), f2bf(a0[3] * inv));
    ushort4 w1 = make_ushort4(f2bf(a1[0] * inv), f2bf(a1[1] * inv), f2bf(a1[2] * inv), f2bf(a1[3] * inv));
    *((ushort4*)op) = w0;
    *((ushort4*)(op + 16)) = w1;
  }
}

// ---------------------------------------------------------------------------
// post: a@Wp + skip -> preLN -> gelu(n@W1''+b1'')@W2 + res -> postLN -> out.
// 8-position tiles, grid 256 (rows 8..15 are clamped duplicates; writes
// masked to lq<8) -> full-GPU coverage for this latency-chain kernel.
// ---------------------------------------------------------------------------
__global__ __launch_bounds__(256) void post_mfma(
    const ushort_t* __restrict__ Ab, const float* __restrict__ skip,
    const ushort_t* __restrict__ WpT, const float* __restrict__ bp,
    const float* __restrict__ pre_g, const float* __restrict__ pre_b,
    const ushort_t* __restrict__ W1T, const float* __restrict__ b1p,
    const ushort_t* __restrict__ W2T, const float* __restrict__ b2,
    const float* __restrict__ post_g, const float* __restrict__ post_b,
    float* __restrict__ out) {
  const int t = threadIdx.x;
  const int w = t >> 6, l = t & 63, lq = l & 15, quad = l >> 4;
  const int b = blockIdx.x >> 7;
  const int p0 = (blockIdx.x & 127) * 8;
  const int rp = (p0 + lq < SQL) ? (p0 + lq) : (SQL - 1);   // clamped row

  __shared__ float zf[16 * 132];
  __shared__ float sRes[16 * 132];
  __shared__ ushort_t sZb[16 * 128];
  __shared__ ushort_t sH[16 * 256];
  __shared__ float sMu[16], sRs[16];

  // ---- GEMM1: z = a@Wp ----
  f32x4 z[2] = {{0.f,0.f,0.f,0.f},{0.f,0.f,0.f,0.f}};
#pragma unroll
  for (int kk = 0; kk < 4; ++kk) {
    const short8 bfr = *((const short8*)(Ab + ((size_t)b * SQL + rp) * 128 + quad * 8 + kk * 32));
#pragma unroll
    for (int ms = 0; ms < 2; ++ms) {
      const short8 afr = *((const short8*)(WpT + (size_t)(w * 32 + ms * 16 + lq) * 128 + quad * 8 + kk * 32));
      z[ms] = MFMA16(afr, bfr, z[ms], 0, 0, 0);
    }
  }
#pragma unroll
  for (int ms = 0; ms < 2; ++ms)
#pragma unroll
    for (int r = 0; r < 4; ++r) {
      const int o = w * 32 + ms * 16 + quad * 4 + r;
      const int rr = (p0 + lq < SQL) ? (p0 + lq) : (SQL - 1);
      zf[lq * 132 + o] = z[ms][r] + bp[o] + skip[(size_t)b * 131072 + (size_t)o * 1024 + rr];
    }
  __syncthreads();
  if (w == 0) {
    const int pos = l & 15, qr = l >> 4;
    float s1 = 0.f, s2 = 0.f;
#pragma unroll
    for (int j = 0; j < 32; ++j) { const float vv = zf[pos * 132 + qr * 32 + j]; s1 += vv; s2 += vv * vv; }
    s1 += __shfl_xor(s1, 16, 64); s1 += __shfl_xor(s1, 32, 64);
    s2 += __shfl_xor(s2, 16, 64); s2 += __shfl_xor(s2, 32, 64);
    const float mu = s1 * (1.f / 128.f);
    if (qr == 0) { sMu[pos] = mu; sRs[pos] = rsqrtf(s2 * (1.f / 128.f) - mu * mu + 1e-5f); }
  }
  __syncthreads();
  {
    const int pos = t & 15, grp = t >> 4;
    const float mu = sMu[pos], rs = sRs[pos];
    short8 pk;
#pragma unroll
    for (int i = 0; i < 8; ++i) {
      const int ch = grp * 8 + i;
      const float nv = (zf[pos * 132 + ch] - mu) * rs;
      pk[i] = (short)f2bf(nv);
      sRes[pos * 132 + ch] = nv * pre_g[ch] + pre_b[ch];
    }
    *((short8*)&sZb[pos * 128 + (grp ^ (pos & 7)) * 8]) = pk;
  }
  __syncthreads();
  // ---- GEMM2 + gelu ----
  f32x4 h[4];
#pragma unroll
  for (int ms = 0; ms < 4; ++ms) h[ms] = (f32x4){0.f, 0.f, 0.f, 0.f};
  short8 bz[4];
#pragma unroll
  for (int kk = 0; kk < 4; ++kk)
    bz[kk] = *((const short8*)&sZb[lq * 128 + ((quad + 4 * kk) ^ (lq & 7)) * 8]);
#pragma unroll
  for (int ms = 0; ms < 4; ++ms)
#pragma unroll
    for (int kk = 0; kk < 4; ++kk) {
      const short8 afr = *((const short8*)(W1T + (size_t)(w * 64 + ms * 16 + lq) * 128 + quad * 8 + kk * 32));
      h[ms] = MFMA16(afr, bz[kk], h[ms], 0, 0, 0);
    }
#pragma unroll
  for (int ms = 0; ms < 4; ++ms)
#pragma unroll
    for (int r = 0; r < 4; ++r) {
      const int o = w * 64 + ms * 16 + quad * 4 + r;
      const float hv = fast_gelu(h[ms][r] + b1p[o]);
      const int phys = (o >> 3) ^ (lq & 7);
      sH[lq * 256 + phys * 8 + (o & 7)] = f2bf(hv);
    }
  __syncthreads();
  // ---- GEMM3 + residual ----
  f32x4 z2[2] = {{0.f,0.f,0.f,0.f},{0.f,0.f,0.f,0.f}};
#pragma unroll
  for (int kk = 0; kk < 8; ++kk) {
    const short8 bh = *((const short8*)&sH[lq * 256 + ((quad + 4 * kk) ^ (lq & 7)) * 8]);
#pragma unroll
    for (int ms = 0; ms < 2; ++ms) {
      const short8 afr = *((const short8*)(W2T + (size_t)(w * 32 + ms * 16 + lq) * 256 + quad * 8 + kk * 32));
      z2[ms] = MFMA16(afr, bh, z2[ms], 0, 0, 0);
    }
  }
  __syncthreads();
#pragma unroll
  for (int ms = 0; ms < 2; ++ms)
#pragma unroll
    for (int r = 0; r < 4; ++r) {
      const int o = w * 32 + ms * 16 + quad * 4 + r;
      zf[lq * 132 + o] = z2[ms][r] + b2[o] + sRes[lq * 132 + o];
    }
  __syncthreads();
  if (w == 0) {
    const int pos = l & 15, qr = l >> 4;
    float s1 = 0.f, s2 = 0.f;
#pragma unroll
    for (int j = 0; j < 32; ++j) { const float vv = zf[pos * 132 + qr * 32 + j]; s1 += vv; s2 += vv * vv; }
    s1 += __shfl_xor(s1, 16, 64); s1 += __shfl_xor(s1, 32, 64);
    s2 += __shfl_xor(s2, 16, 64); s2 += __shfl_xor(s2, 32, 64);
    const float mu = s1 * (1.f / 128.f);
    if (qr == 0) { sMu[pos] = mu; sRs[pos] = rsqrtf(s2 * (1.f / 128.f) - mu * mu + 1e-5f); }
  }
  __syncthreads();
  {
    const int pos = t & 15, grp = t >> 4;
    if (pos < 8) {
      const float mu = sMu[pos], rs = sRs[pos];
#pragma unroll
      for (int i = 0; i < 8; ++i) {
        const int ch = grp * 8 + i;
        out[(size_t)b * 131072 + (size_t)ch * 1024 + p0 + pos] =
            (zf[pos * 132 + ch] - mu) * rs * post_g[ch] + post_b[ch];
      }
    }
  }
}

// ---------------------------------------------------------------------------
extern "C" void kernel_launch(void* const* d_in, const int* in_sizes, int n_in,
                              void* d_out, int out_size, void* d_ws, size_t ws_size,
                              hipStream_t stream) {
  const float* q_in   = (const float*)d_in[0];
  const float* k_in   = (const float*)d_in[1];
  const float* v_in   = (const float*)d_in[2];
  const float* skip   = (const float*)d_in[3];
  const float* q_ln_g = (const float*)d_in[4];
  const float* q_ln_b = (const float*)d_in[5];
  const float* Wq     = (const float*)d_in[6];
  const float* bq     = (const float*)d_in[7];
  const float* k_ln_g = (const float*)d_in[8];
  const float* k_ln_b = (const float*)d_in[9];
  const float* Wk     = (const float*)d_in[10];
  const float* bk     = (const float*)d_in[11];
  const float* v_ln_g = (const float*)d_in[12];
  const float* v_ln_b = (const float*)d_in[13];
  const float* Wv     = (const float*)d_in[14];
  const float* bv     = (const float*)d_in[15];
  const float* Wp     = (const float*)d_in[16];
  const float* bp     = (const float*)d_in[17];
  const float* pre_g  = (const float*)d_in[18];
  const float* pre_b  = (const float*)d_in[19];
  const float* W1     = (const float*)d_in[20];
  const float* b1     = (const float*)d_in[21];
  const float* W2     = (const float*)d_in[22];
  const float* b2     = (const float*)d_in[23];
  const float* post_g = (const float*)d_in[24];
  const float* post_b = (const float*)d_in[25];

  char* base = (char*)d_ws;
  ushort_t* WqT = (ushort_t*)base; base += 16384 * 2;
  ushort_t* WkT = (ushort_t*)base; base += 16384 * 2;
  ushort_t* WvT = (ushort_t*)base; base += 16384 * 2;
  ushort_t* WpT = (ushort_t*)base; base += 16384 * 2;
  ushort_t* W1T = (ushort_t*)base; base += 32768 * 2;
  ushort_t* W2T = (ushort_t*)base; base += 32768 * 2;
  float* uq  = (float*)base; base += 128 * 4;
  float* bbq = (float*)base; base += 128 * 4;
  float* uk  = (float*)base; base += 128 * 4;
  float* bbk = (float*)base; base += 128 * 4;
  float* uv  = (float*)base; base += 128 * 4;
  float* bbv = (float*)base; base += 128 * 4;
  float* b1p = (float*)base; base += 256 * 4;
  base = (char*)(((size_t)base + 255) & ~(size_t)255);
  ushort_t* Qh = (ushort_t*)base; base += (size_t)1572864 * 2;
  ushort_t* Kh = (ushort_t*)base; base += (size_t)(2580480 + 4096) * 2;
  ushort_t* Vt = (ushort_t*)base; base += (size_t)(2580480 + 4096) * 2;
  ushort_t* Ab = (ushort_t*)base; base += (size_t)262144 * 2;
  float* out = (float*)d_out;

  prep_kernel<<<28, 256, 0, stream>>>(
      Wq, q_ln_g, q_ln_b, bq, Wk, k_ln_g, k_ln_b, bk, Wv, v_ln_g, v_ln_b, bv,
      Wp, W1, pre_g, pre_b, b1, W2,
      WqT, WkT, WvT, WpT, W1T, W2T, uq, bbq, uk, bbk, uv, bbv, b1p);
  proj_mfma<<<840, 256, 0, stream>>>(
      q_in, k_in, v_in, WqT, WkT, WvT, uq, uk, uv, bbq, bbk, bbv, Qh, Kh, Vt);
  attn_mfma<<<256, 512, 0, stream>>>(Qh, Kh, Vt, Ab);
  post_mfma<<<256, 256, 0, stream>>>(
      Ab, skip, WpT, bp, pre_g, pre_b, W1T, b1p, W2T, b2, post_g, post_b, out);
}